// Round 2
// baseline (7748.943 us; speedup 1.0000x reference)
//
#include <hip/hip_runtime.h>
#include <math.h>

#define CC   1024
#define HH   16
#define DH   64
#define TT   512
#define BB   2
#define NTOK 1024     // B*T
#define DFF_ 4096
#define VV   32000
#define QKSCALE 0.125f   // 1/sqrt(64)

// ---------------- embedding: x[row,c] = wte[idx[row],c] + wpe[row%T,c] ----
__global__ __launch_bounds__(256) void embed_kernel(
    const int* __restrict__ idx, const float* __restrict__ wte,
    const float* __restrict__ wpe, float* __restrict__ x) {
  int row = blockIdx.x;            // 0..1023
  int t = row & (TT - 1);
  int id = idx[row];
  const float4* a = (const float4*)(wte + (size_t)id * CC);
  const float4* p = (const float4*)(wpe + (size_t)t * CC);
  float4* o = (float4*)(x + (size_t)row * CC);
  int c = threadIdx.x;             // 256 threads, 4 floats each
  float4 va = a[c], vp = p[c];
  float4 ov;
  ov.x = va.x + vp.x; ov.y = va.y + vp.y; ov.z = va.z + vp.z; ov.w = va.w + vp.w;
  o[c] = ov;
}

// ---------------- layernorm: one block per row ---------------------------
__global__ __launch_bounds__(256) void ln_kernel(
    const float* __restrict__ x, const float* __restrict__ w,
    const float* __restrict__ b, float* __restrict__ out) {
  int row = blockIdx.x, tid = threadIdx.x;
  float4 v = ((const float4*)(x + (size_t)row * CC))[tid];
  float s  = v.x + v.y + v.z + v.w;
  float sq = fmaf(v.x, v.x, fmaf(v.y, v.y, fmaf(v.z, v.z, v.w * v.w)));
  for (int o = 32; o > 0; o >>= 1) { s += __shfl_down(s, o); sq += __shfl_down(sq, o); }
  __shared__ float rs[4], rq[4];
  int wid = tid >> 6, lane = tid & 63;
  if (lane == 0) { rs[wid] = s; rq[wid] = sq; }
  __syncthreads();
  s  = rs[0] + rs[1] + rs[2] + rs[3];
  sq = rq[0] + rq[1] + rq[2] + rq[3];
  float mean = s * (1.0f / CC);
  float var  = sq * (1.0f / CC) - mean * mean;
  float rstd = 1.0f / sqrtf(var + 1e-5f);
  float4 wv = ((const float4*)w)[tid];
  float4 bv = ((const float4*)b)[tid];
  float4 o;
  o.x = (v.x - mean) * rstd * wv.x + bv.x;
  o.y = (v.y - mean) * rstd * wv.y + bv.y;
  o.z = (v.z - mean) * rstd * wv.z + bv.z;
  o.w = (v.w - mean) * rstd * wv.w + bv.w;
  ((float4*)(out + (size_t)row * CC))[tid] = o;
}

// ---------------- softmax over rows of att (causal already -inf'd) -------
__global__ __launch_bounds__(256) void softmax_kernel(float* __restrict__ att) {
  size_t row = blockIdx.x;                 // 0 .. 32*512-1
  float* p = att + row * (size_t)TT;
  int tid = threadIdx.x;
  float2 v = ((float2*)p)[tid];            // 2 elems each (512/256)
  __shared__ float red[4];
  int wid = tid >> 6, lane = tid & 63;
  float m = fmaxf(v.x, v.y);
  for (int o = 32; o > 0; o >>= 1) m = fmaxf(m, __shfl_down(m, o));
  if (lane == 0) red[wid] = m;
  __syncthreads();
  m = fmaxf(fmaxf(red[0], red[1]), fmaxf(red[2], red[3]));
  float e0 = expf(v.x - m), e1 = expf(v.y - m);
  float s = e0 + e1;
  for (int o = 32; o > 0; o >>= 1) s += __shfl_down(s, o);
  __syncthreads();
  if (lane == 0) red[wid] = s;
  __syncthreads();
  s = red[0] + red[1] + red[2] + red[3];
  float inv = 1.0f / s;
  ((float2*)p)[tid] = make_float2(e0 * inv, e1 * inv);
}

// ---------------- generic tiled GEMM -------------------------------------
// C[M,N] = epi(A[M,K] @ B + bias), B row-major [K,N] (TB=0) or [N,K] (TB=1)
// EPI: 0 = bias-or-none, 1 = residual add into C, 2 = gelu(.+bias),
//      3 = scale + causal mask (attention scores)
// Batched over blockIdx.z: z = b*16 + h, with per-(b) and per-(h) strides.
__device__ inline float gelu_f(float h) {
  return 0.5f * h * (1.0f + tanhf(0.7978845608028654f * (h + 0.044715f * h * h * h)));
}

template <bool TB, int EPI>
__global__ __launch_bounds__(256) void gemm_kernel(
    const float* __restrict__ A, const float* __restrict__ Bm,
    const float* __restrict__ bias, float* __restrict__ Cm,
    int M, int N, int K, int lda, int ldb, int ldc,
    long aB, long aH, long bB, long bH, long cB, long cH) {
  int z = blockIdx.z;
  A  += (size_t)(z >> 4) * aB + (size_t)(z & 15) * aH;
  Bm += (size_t)(z >> 4) * bB + (size_t)(z & 15) * bH;
  Cm += (size_t)(z >> 4) * cB + (size_t)(z & 15) * cH;
  int row0 = blockIdx.y * 64, col0 = blockIdx.x * 64;

  __shared__ __align__(16) float As[16][64];
  __shared__ __align__(16) float Bs[16][64];
  int tid = threadIdx.x;
  int tx = tid & 15, ty = tid >> 4;
  float acc[4][4] = {};

  for (int k0 = 0; k0 < K; k0 += 16) {
    {  // A tile -> As[k][m] (k-major)
      int m  = tid >> 2;
      int kk = (tid & 3) * 4;
      float4 vA = *(const float4*)(A + (size_t)(row0 + m) * lda + k0 + kk);
      As[kk + 0][m] = vA.x; As[kk + 1][m] = vA.y;
      As[kk + 2][m] = vA.z; As[kk + 3][m] = vA.w;
    }
    if (!TB) {  // B tile row-major [K,N] -> Bs[k][n]
      int kk = tid >> 4;
      int n  = (tid & 15) * 4;
      float4 vB = *(const float4*)(Bm + (size_t)(k0 + kk) * ldb + col0 + n);
      *(float4*)&Bs[kk][n] = vB;
    } else {    // B stored [N,K] -> Bs[k][n]
      int n  = tid >> 2;
      int kk = (tid & 3) * 4;
      float4 vB = *(const float4*)(Bm + (size_t)(col0 + n) * ldb + k0 + kk);
      Bs[kk + 0][n] = vB.x; Bs[kk + 1][n] = vB.y;
      Bs[kk + 2][n] = vB.z; Bs[kk + 3][n] = vB.w;
    }
    __syncthreads();
#pragma unroll
    for (int k = 0; k < 16; ++k) {
      float4 a4 = *(const float4*)&As[k][ty * 4];
      float4 b4 = *(const float4*)&Bs[k][tx * 4];
      float av[4] = {a4.x, a4.y, a4.z, a4.w};
      float bv[4] = {b4.x, b4.y, b4.z, b4.w};
#pragma unroll
      for (int i = 0; i < 4; ++i)
#pragma unroll
        for (int j = 0; j < 4; ++j)
          acc[i][j] = fmaf(av[i], bv[j], acc[i][j]);
    }
    __syncthreads();
  }

  float bj[4] = {0.f, 0.f, 0.f, 0.f};
  if (EPI != 3 && bias != nullptr) {
    float4 bb = *(const float4*)(bias + col0 + tx * 4);
    bj[0] = bb.x; bj[1] = bb.y; bj[2] = bb.z; bj[3] = bb.w;
  }
#pragma unroll
  for (int i = 0; i < 4; ++i) {
    int r = row0 + ty * 4 + i;
    float* crow = Cm + (size_t)r * ldc + col0 + tx * 4;
    float4 o;
    float vals[4];
#pragma unroll
    for (int j = 0; j < 4; ++j) {
      float vv = acc[i][j] + bj[j];
      if (EPI == 2) vv = gelu_f(vv);
      if (EPI == 3) {
        vv = acc[i][j] * QKSCALE;
        int jg = col0 + tx * 4 + j;
        if (jg > r) vv = -INFINITY;   // causal mask (r = query idx within batch)
      }
      vals[j] = vv;
    }
    if (EPI == 1) {
      float4 old = *(float4*)crow;
      vals[0] += old.x; vals[1] += old.y; vals[2] += old.z; vals[3] += old.w;
    }
    o.x = vals[0]; o.y = vals[1]; o.z = vals[2]; o.w = vals[3];
    *(float4*)crow = o;
  }
}

// ---------------- launch ---------------------------------------------------
#define GEMM(TB, EPI, A_, B_, BIAS_, C_, M_, N_, K_, LDA_, LDB_, LDC_, Z_, AB_, AH_, BB_, BH_, CB_, CH_) \
  gemm_kernel<TB, EPI><<<dim3((N_) / 64, (M_) / 64, (Z_)), 256, 0, stream>>>( \
      A_, B_, BIAS_, C_, M_, N_, K_, LDA_, LDB_, LDC_, AB_, AH_, BB_, BH_, CB_, CH_)

extern "C" void kernel_launch(void* const* d_in, const int* in_sizes, int n_in,
                              void* d_out, int out_size, void* d_ws, size_t ws_size,
                              hipStream_t stream) {
  const int*   idx   = (const int*)d_in[0];
  const float* xa    = (const float*)d_in[1];
  const float* wte   = (const float*)d_in[2];
  const float* wpe   = (const float*)d_in[3];
  const float* ln1_w = (const float*)d_in[4];
  const float* ln1_b = (const float*)d_in[5];
  const float* sa_wq = (const float*)d_in[6];
  const float* sa_bq = (const float*)d_in[7];
  const float* sa_wk = (const float*)d_in[8];
  const float* sa_bk = (const float*)d_in[9];
  const float* sa_wv = (const float*)d_in[10];
  const float* sa_bv = (const float*)d_in[11];
  const float* sa_wo = (const float*)d_in[12];
  const float* sa_bo = (const float*)d_in[13];
  const float* ca_wq = (const float*)d_in[14];
  const float* ca_bq = (const float*)d_in[15];
  const float* ca_wk = (const float*)d_in[16];
  const float* ca_bk = (const float*)d_in[17];
  const float* ca_wv = (const float*)d_in[18];
  const float* ca_bv = (const float*)d_in[19];
  const float* ca_wo = (const float*)d_in[20];
  const float* ca_bo = (const float*)d_in[21];
  const float* ln2_w = (const float*)d_in[22];
  const float* ln2_b = (const float*)d_in[23];
  const float* fc_w  = (const float*)d_in[24];
  const float* fc_b  = (const float*)d_in[25];
  const float* pr_w  = (const float*)d_in[26];
  const float* pr_b  = (const float*)d_in[27];
  const float* lnf_w = (const float*)d_in[28];
  const float* lnf_b = (const float*)d_in[29];

  float* ws = (float*)d_ws;
  float* x   = ws;                       // [1024,1024]
  float* n   = x + (size_t)NTOK * CC;    // [1024,1024]
  float* q   = n + (size_t)NTOK * CC;
  float* k   = q + (size_t)NTOK * CC;
  float* v   = k + (size_t)NTOK * CC;
  float* y   = v + (size_t)NTOK * CC;
  float* hm  = y + (size_t)NTOK * CC;    // [1024,4096]
  float* att = hm + (size_t)NTOK * DFF_; // [32,512,512]

  const long sBH = (long)TT * CC;   // per-b stride in token matrices
  const long sHH = (long)DH;        // per-head col offset
  const long sAB = (long)HH * TT * TT;  // att per-b
  const long sAH = (long)TT * TT;       // att per-h

  embed_kernel<<<NTOK, 256, 0, stream>>>(idx, wte, wpe, x);

  for (int l = 0; l < 6; ++l) {
    size_t wofs = (size_t)l * CC * CC;
    size_t bofs = (size_t)l * CC;

    // ---- self attention ----
    ln_kernel<<<NTOK, 256, 0, stream>>>(x, ln1_w + bofs, ln1_b + bofs, n);
    GEMM(false, 0, n, sa_wq + wofs, sa_bq + bofs, q, NTOK, CC, CC, CC, CC, CC, 1, 0, 0, 0, 0, 0, 0);
    GEMM(false, 0, n, sa_wk + wofs, sa_bk + bofs, k, NTOK, CC, CC, CC, CC, CC, 1, 0, 0, 0, 0, 0, 0);
    GEMM(false, 0, n, sa_wv + wofs, sa_bv + bofs, v, NTOK, CC, CC, CC, CC, CC, 1, 0, 0, 0, 0, 0, 0);
    GEMM(true, 3, q, k, nullptr, att, TT, TT, DH, CC, CC, TT, 32, sBH, sHH, sBH, sHH, sAB, sAH);
    softmax_kernel<<<32 * TT, 256, 0, stream>>>(att);
    GEMM(false, 0, att, v, nullptr, y, TT, DH, TT, TT, CC, CC, 32, sAB, sAH, sBH, sHH, sBH, sHH);
    GEMM(false, 1, y, sa_wo + wofs, sa_bo + bofs, x, NTOK, CC, CC, CC, CC, CC, 1, 0, 0, 0, 0, 0, 0);

    // ---- cross attention (ln_1 reused; kv from raw xa; causal mask kept) ----
    ln_kernel<<<NTOK, 256, 0, stream>>>(x, ln1_w + bofs, ln1_b + bofs, n);
    GEMM(false, 0, n,  ca_wq + wofs, ca_bq + bofs, q, NTOK, CC, CC, CC, CC, CC, 1, 0, 0, 0, 0, 0, 0);
    GEMM(false, 0, xa, ca_wk + wofs, ca_bk + bofs, k, NTOK, CC, CC, CC, CC, CC, 1, 0, 0, 0, 0, 0, 0);
    GEMM(false, 0, xa, ca_wv + wofs, ca_bv + bofs, v, NTOK, CC, CC, CC, CC, CC, 1, 0, 0, 0, 0, 0, 0);
    GEMM(true, 3, q, k, nullptr, att, TT, TT, DH, CC, CC, TT, 32, sBH, sHH, sBH, sHH, sAB, sAH);
    softmax_kernel<<<32 * TT, 256, 0, stream>>>(att);
    GEMM(false, 0, att, v, nullptr, y, TT, DH, TT, TT, CC, CC, 32, sAB, sAH, sBH, sHH, sBH, sHH);
    GEMM(false, 1, y, ca_wo + wofs, ca_bo + bofs, x, NTOK, CC, CC, CC, CC, CC, 1, 0, 0, 0, 0, 0, 0);

    // ---- MLP ----
    ln_kernel<<<NTOK, 256, 0, stream>>>(x, ln2_w + bofs, ln2_b + bofs, n);
    GEMM(false, 2, n, fc_w + (size_t)l * CC * DFF_, fc_b + (size_t)l * DFF_, hm,
         NTOK, DFF_, CC, CC, DFF_, DFF_, 1, 0, 0, 0, 0, 0, 0);
    GEMM(false, 1, hm, pr_w + (size_t)l * DFF_ * CC, pr_b + bofs, x,
         NTOK, CC, DFF_, DFF_, CC, CC, 1, 0, 0, 0, 0, 0, 0);
  }

  // ---- final LN + tied lm_head (x @ wte^T) ----
  ln_kernel<<<NTOK, 256, 0, stream>>>(x, lnf_w, lnf_b, n);
  GEMM(true, 0, n, wte, nullptr, (float*)d_out, NTOK, VV, CC, CC, CC, VV, 1, 0, 0, 0, 0, 0, 0);
}

// Round 5
// 2974.885 us; speedup vs baseline: 2.6048x; 2.6048x over previous
//
#include <hip/hip_runtime.h>
#include <math.h>

#define CC   1024
#define HH   16
#define DH   64
#define TT   512
#define NTOK 1024     // B*T
#define DFF_ 4096
#define VV   32000
#define QKSCALE 0.125f   // 1/sqrt(64)

typedef unsigned short u16;
typedef __attribute__((ext_vector_type(8))) short short8;
typedef __attribute__((ext_vector_type(4))) float f32x4;

__device__ __forceinline__ u16 f2bf(float f) {   // RNE fp32->bf16
  union { float f; unsigned u; } v; v.f = f;
  unsigned r = v.u + 0x7FFFu + ((v.u >> 16) & 1u);
  return (u16)(r >> 16);
}
__device__ __forceinline__ float gelu_f(float h) {
  return 0.5f * h * (1.0f + tanhf(0.7978845608028654f * (h + 0.044715f * h * h * h)));
}

// async global->LDS, 16B per lane; dest must be wave-uniform base (lane*16 auto)
#define GLD16(gp, lp) __builtin_amdgcn_global_load_lds( \
    (const __attribute__((address_space(1))) void*)(gp), \
    (__attribute__((address_space(3))) void*)(lp), 16, 0, 0)

// ---------------- embedding ----------------------------------------------
__global__ __launch_bounds__(256) void embed_kernel(
    const int* __restrict__ idx, const float* __restrict__ wte,
    const float* __restrict__ wpe, float* __restrict__ x) {
  int row = blockIdx.x;
  int t = row & (TT - 1);
  int id = idx[row];
  const float4* a = (const float4*)(wte + (size_t)id * CC);
  const float4* p = (const float4*)(wpe + (size_t)t * CC);
  float4* o = (float4*)(x + (size_t)row * CC);
  int c = threadIdx.x;
  float4 va = a[c], vp = p[c];
  float4 ov;
  ov.x = va.x + vp.x; ov.y = va.y + vp.y; ov.z = va.z + vp.z; ov.w = va.w + vp.w;
  o[c] = ov;
}

// ---------------- layernorm (fp32 in -> bf16 out) ------------------------
__global__ __launch_bounds__(256) void ln_kernel(
    const float* __restrict__ x, const float* __restrict__ w,
    const float* __restrict__ b, u16* __restrict__ out) {
  int row = blockIdx.x, tid = threadIdx.x;
  float4 v = ((const float4*)(x + (size_t)row * CC))[tid];
  float s  = v.x + v.y + v.z + v.w;
  float sq = fmaf(v.x, v.x, fmaf(v.y, v.y, fmaf(v.z, v.z, v.w * v.w)));
  for (int o = 32; o > 0; o >>= 1) { s += __shfl_down(s, o); sq += __shfl_down(sq, o); }
  __shared__ float rs[4], rq[4];
  int wid = tid >> 6, lane = tid & 63;
  if (lane == 0) { rs[wid] = s; rq[wid] = sq; }
  __syncthreads();
  s  = rs[0] + rs[1] + rs[2] + rs[3];
  sq = rq[0] + rq[1] + rq[2] + rq[3];
  float mean = s * (1.0f / CC);
  float var  = sq * (1.0f / CC) - mean * mean;
  float rstd = 1.0f / sqrtf(var + 1e-5f);
  float4 wv = ((const float4*)w)[tid];
  float4 bv = ((const float4*)b)[tid];
  ushort4 o;
  o.x = f2bf((v.x - mean) * rstd * wv.x + bv.x);
  o.y = f2bf((v.y - mean) * rstd * wv.y + bv.y);
  o.z = f2bf((v.z - mean) * rstd * wv.z + bv.z);
  o.w = f2bf((v.w - mean) * rstd * wv.w + bv.w);
  ((ushort4*)(out + (size_t)row * CC))[tid] = o;
}

// ---------------- softmax ------------------------------------------------
__global__ __launch_bounds__(256) void softmax_kernel(float* __restrict__ att) {
  size_t row = blockIdx.x;
  float* p = att + row * (size_t)TT;
  int tid = threadIdx.x;
  float2 v = ((float2*)p)[tid];
  __shared__ float red[4];
  int wid = tid >> 6, lane = tid & 63;
  float m = fmaxf(v.x, v.y);
  for (int o = 32; o > 0; o >>= 1) m = fmaxf(m, __shfl_down(m, o));
  if (lane == 0) red[wid] = m;
  __syncthreads();
  m = fmaxf(fmaxf(red[0], red[1]), fmaxf(red[2], red[3]));
  float e0 = expf(v.x - m), e1 = expf(v.y - m);
  float s = e0 + e1;
  for (int o = 32; o > 0; o >>= 1) s += __shfl_down(s, o);
  __syncthreads();
  if (lane == 0) red[wid] = s;
  __syncthreads();
  s = red[0] + red[1] + red[2] + red[3];
  float inv = 1.0f / s;
  ((float2*)p)[tid] = make_float2(e0 * inv, e1 * inv);
}

// ---------------- weight transpose+convert: w[K,N] f32 -> wt[N,K] bf16 ---
__global__ __launch_bounds__(256) void wtrans_kernel(
    const float* __restrict__ w, u16* __restrict__ wt, int Kd, int Nd) {
  __shared__ float t[32][33];
  int bx = blockIdx.x * 32, by = blockIdx.y * 32;
  int c = threadIdx.x & 31, r = threadIdx.x >> 5;   // 8 rows/pass
#pragma unroll
  for (int i = 0; i < 4; ++i)
    t[r + i * 8][c] = w[(size_t)(by + r + i * 8) * Nd + bx + c];
  __syncthreads();
#pragma unroll
  for (int i = 0; i < 4; ++i)
    wt[(size_t)(bx + r + i * 8) * Kd + by + c] = f2bf(t[c][r + i * 8]);
}

// ---------------- elementwise f32 -> bf16 --------------------------------
__global__ __launch_bounds__(256) void convbf_kernel(
    const float* __restrict__ in, u16* __restrict__ out, int n4) {
  int i = blockIdx.x * 256 + threadIdx.x;
  if (i < n4) {
    float4 v = ((const float4*)in)[i];
    ushort4 o; o.x = f2bf(v.x); o.y = f2bf(v.y); o.z = f2bf(v.z); o.w = f2bf(v.w);
    ((ushort4*)out)[i] = o;
  }
}

// ---------------- small f32 copy (bias concat) ---------------------------
__global__ __launch_bounds__(256) void copyf_kernel(
    const float* __restrict__ s, float* __restrict__ d, int n) {
  int i = blockIdx.x * 256 + threadIdx.x;
  if (i < n) d[i] = s[i];
}

// ---------------- bf16 MFMA GEMM (m97 structure) -------------------------
// C[M,N](ldc) = epi(A[M,K] @ B^T + bias);  A[M,K], B[N,K] both bf16 row-major.
// 128x128 tile, BK=32, 4 waves of 64x64. EPI: 0=store f32(+bias),
// 1=f32 += (+bias) residual, 2=bf16 gelu(+bias)
template <int EPI>
__global__ __launch_bounds__(256) void gemm_bf16_kernel(
    const u16* __restrict__ A, const u16* __restrict__ B,
    const float* __restrict__ bias, float* __restrict__ Cm,
    int K, int ldc) {
  __shared__ u16 As[128 * 32];
  __shared__ u16 Bs[128 * 32];
  int tid = threadIdx.x;
  int lane = tid & 63, wave = tid >> 6;
  int wr = wave >> 1, wc = wave & 1;
  int row0 = blockIdx.y * 128, col0 = blockIdx.x * 128;
  f32x4 acc[4][4];
#pragma unroll
  for (int m = 0; m < 4; ++m)
#pragma unroll
    for (int n = 0; n < 4; ++n) acc[m][n] = (f32x4){0.f, 0.f, 0.f, 0.f};

  int lr = lane >> 2;           // 0..15: row within 16-row chunk
  int lk = (lane & 3) * 8;      // k elem offset (8 bf16 = 16B)
  const u16* Ab = A + (size_t)row0 * K;
  const u16* Bb = B + (size_t)col0 * K;
  int arow = wr * 64 + (lane & 15);
  int brow = wc * 64 + (lane & 15);
  int kof = (lane >> 4) * 8;

  for (int k0 = 0; k0 < K; k0 += 32) {
#pragma unroll
    for (int i = 0; i < 2; ++i) {
      int c = i * 4 + wave;     // chunk = 16 rows of the 128-row tile
      GLD16(Ab + (size_t)(c * 16 + lr) * K + k0 + lk, &As[c * 512]);
      GLD16(Bb + (size_t)(c * 16 + lr) * K + k0 + lk, &Bs[c * 512]);
    }
    __syncthreads();            // compiler inserts vmcnt(0) drain
    short8 af[4], bg[4];
#pragma unroll
    for (int m = 0; m < 4; ++m) af[m] = *(const short8*)&As[(arow + m * 16) * 32 + kof];
#pragma unroll
    for (int n = 0; n < 4; ++n) bg[n] = *(const short8*)&Bs[(brow + n * 16) * 32 + kof];
#pragma unroll
    for (int m = 0; m < 4; ++m)
#pragma unroll
      for (int n = 0; n < 4; ++n)
        acc[m][n] = __builtin_amdgcn_mfma_f32_16x16x32_bf16(af[m], bg[n], acc[m][n], 0, 0, 0);
    __syncthreads();
  }

  float bj[4];
#pragma unroll
  for (int n = 0; n < 4; ++n)
    bj[n] = bias ? bias[col0 + wc * 64 + n * 16 + (lane & 15)] : 0.0f;
  int r0 = row0 + wr * 64 + (lane >> 4) * 4;
  int c0 = col0 + wc * 64 + (lane & 15);
  u16* Cb = (u16*)Cm;
#pragma unroll
  for (int m = 0; m < 4; ++m)
#pragma unroll
    for (int n = 0; n < 4; ++n)
#pragma unroll
      for (int r = 0; r < 4; ++r) {
        size_t off = (size_t)(r0 + m * 16 + r) * ldc + c0 + n * 16;
        float v = acc[m][n][r] + bj[n];
        if (EPI == 0) Cm[off] = v;
        else if (EPI == 1) Cm[off] += v;
        else Cb[off] = f2bf(gelu_f(v));
      }
}

// ---------------- fp32 tiled GEMM (attention core only) ------------------
// EPI: 0 = plain, 3 = scale+causal. OUTBF: store bf16 instead of f32.
template <bool TB, int EPI, bool OUTBF>
__global__ __launch_bounds__(256) void gemm_kernel(
    const float* __restrict__ A, const float* __restrict__ Bm,
    float* __restrict__ Cm,
    int K, int lda, int ldb, int ldc,
    long aB, long aH, long bB, long bH, long cB, long cH) {
  int z = blockIdx.z;
  A  += (size_t)(z >> 4) * aB + (size_t)(z & 15) * aH;
  Bm += (size_t)(z >> 4) * bB + (size_t)(z & 15) * bH;
  size_t czoff = (size_t)(z >> 4) * cB + (size_t)(z & 15) * cH;
  int row0 = blockIdx.y * 64, col0 = blockIdx.x * 64;

  __shared__ __align__(16) float As[16][64];
  __shared__ __align__(16) float Bs[16][64];
  int tid = threadIdx.x;
  int tx = tid & 15, ty = tid >> 4;
  float acc[4][4] = {};

  for (int k0 = 0; k0 < K; k0 += 16) {
    {
      int m  = tid >> 2;
      int kk = (tid & 3) * 4;
      float4 vA = *(const float4*)(A + (size_t)(row0 + m) * lda + k0 + kk);
      As[kk + 0][m] = vA.x; As[kk + 1][m] = vA.y;
      As[kk + 2][m] = vA.z; As[kk + 3][m] = vA.w;
    }
    if (!TB) {
      int kk = tid >> 4;
      int n  = (tid & 15) * 4;
      float4 vB = *(const float4*)(Bm + (size_t)(k0 + kk) * ldb + col0 + n);
      *(float4*)&Bs[kk][n] = vB;
    } else {
      int n  = tid >> 2;
      int kk = (tid & 3) * 4;
      float4 vB = *(const float4*)(Bm + (size_t)(col0 + n) * ldb + k0 + kk);
      Bs[kk + 0][n] = vB.x; Bs[kk + 1][n] = vB.y;
      Bs[kk + 2][n] = vB.z; Bs[kk + 3][n] = vB.w;
    }
    __syncthreads();
#pragma unroll
    for (int k = 0; k < 16; ++k) {
      float4 a4 = *(const float4*)&As[k][ty * 4];
      float4 b4 = *(const float4*)&Bs[k][tx * 4];
      float av[4] = {a4.x, a4.y, a4.z, a4.w};
      float bv[4] = {b4.x, b4.y, b4.z, b4.w};
#pragma unroll
      for (int i = 0; i < 4; ++i)
#pragma unroll
        for (int j = 0; j < 4; ++j)
          acc[i][j] = fmaf(av[i], bv[j], acc[i][j]);
    }
    __syncthreads();
  }

#pragma unroll
  for (int i = 0; i < 4; ++i) {
    int r = row0 + ty * 4 + i;
    float vals[4];
#pragma unroll
    for (int j = 0; j < 4; ++j) {
      float vv = acc[i][j];
      if (EPI == 3) {
        vv *= QKSCALE;
        int jg = col0 + tx * 4 + j;
        if (jg > r) vv = -INFINITY;
      }
      vals[j] = vv;
    }
    if (OUTBF) {
      u16* crow = (u16*)Cm + czoff + (size_t)r * ldc + col0 + tx * 4;
      ushort4 o;
      o.x = f2bf(vals[0]); o.y = f2bf(vals[1]); o.z = f2bf(vals[2]); o.w = f2bf(vals[3]);
      *(ushort4*)crow = o;
    } else {
      float* crow = Cm + czoff + (size_t)r * ldc + col0 + tx * 4;
      float4 o; o.x = vals[0]; o.y = vals[1]; o.z = vals[2]; o.w = vals[3];
      *(float4*)crow = o;
    }
  }
}

// ---------------- launch ---------------------------------------------------
extern "C" void kernel_launch(void* const* d_in, const int* in_sizes, int n_in,
                              void* d_out, int out_size, void* d_ws, size_t ws_size,
                              hipStream_t stream) {
  const int*   idx   = (const int*)d_in[0];
  const float* xa    = (const float*)d_in[1];
  const float* wte   = (const float*)d_in[2];
  const float* wpe   = (const float*)d_in[3];
  const float* ln1_w = (const float*)d_in[4];
  const float* ln1_b = (const float*)d_in[5];
  const float* sa_wq = (const float*)d_in[6];
  const float* sa_bq = (const float*)d_in[7];
  const float* sa_wk = (const float*)d_in[8];
  const float* sa_bk = (const float*)d_in[9];
  const float* sa_wv = (const float*)d_in[10];
  const float* sa_bv = (const float*)d_in[11];
  const float* sa_wo = (const float*)d_in[12];
  const float* sa_bo = (const float*)d_in[13];
  const float* ca_wq = (const float*)d_in[14];
  const float* ca_bq = (const float*)d_in[15];
  const float* ca_wk = (const float*)d_in[16];
  const float* ca_bk = (const float*)d_in[17];
  const float* ca_wv = (const float*)d_in[18];
  const float* ca_bv = (const float*)d_in[19];
  const float* ca_wo = (const float*)d_in[20];
  const float* ca_bo = (const float*)d_in[21];
  const float* ln2_w = (const float*)d_in[22];
  const float* ln2_b = (const float*)d_in[23];
  const float* fc_w  = (const float*)d_in[24];
  const float* fc_b  = (const float*)d_in[25];
  const float* pr_w  = (const float*)d_in[26];
  const float* pr_b  = (const float*)d_in[27];
  const float* lnf_w = (const float*)d_in[28];
  const float* lnf_b = (const float*)d_in[29];

  const size_t M1 = 1048576;
  float* ws     = (float*)d_ws;
  float* x      = ws;                    // [1024,1024] f32
  float* qkv    = x + M1;                // [1024,3072] f32 (q|k|v cols)
  float* att    = qkv + 3 * M1;          // [32,512,512] f32
  float* qkv_b  = att + 8 * M1;          // [3072] (+pad)
  float* cakv_b = qkv_b + 4096;          // [2048]
  u16* nbf   = (u16*)(cakv_b + 2048);    // [1024,1024] bf16
  u16* ybf   = nbf + M1;                 // [1024,1024] bf16
  u16* hmbf  = ybf + M1;                 // [1024,4096] bf16
  u16* xabf  = hmbf + 4 * M1;            // [1024,1024] bf16
  u16* wtebf = xabf + M1;                // [32000,1024] bf16
  u16* wT    = wtebf + (size_t)VV * CC;  // 16M bf16: per-layer transposed weights

  // per-layer wT offsets (elems)
  const size_t oQKV = 0, oWO = 3 * M1, oCQ = 4 * M1, oCKV = 5 * M1,
               oCWO = 7 * M1, oFC = 8 * M1, oPR = 12 * M1;

  // strides for attention batched GEMMs (z = b*16 + h)
  const long qB = (long)TT * 3072, qH = DH;          // q/k/v inside qkv buffer
  const long aB = (long)HH * TT * TT, aH = (long)TT * TT;
  const long yB = (long)TT * CC, yH = DH;            // y_bf (u16 units)

  embed_kernel<<<NTOK, 256, 0, stream>>>(idx, wte, wpe, x);
  convbf_kernel<<<(VV * CC / 4 + 255) / 256, 256, 0, stream>>>(wte, wtebf, VV * CC / 4);
  convbf_kernel<<<(NTOK * CC / 4 + 255) / 256, 256, 0, stream>>>(xa, xabf, NTOK * CC / 4);

  for (int l = 0; l < 6; ++l) {
    size_t wofs = (size_t)l * CC * CC;
    size_t bofs = (size_t)l * CC;
    size_t mofs = (size_t)l * CC * DFF_;

    // ---- weight prep (transpose fp32 [K,N] -> bf16 [N,K]) ----
    wtrans_kernel<<<dim3(32, 32), 256, 0, stream>>>(sa_wq + wofs, wT + oQKV, CC, CC);
    wtrans_kernel<<<dim3(32, 32), 256, 0, stream>>>(sa_wk + wofs, wT + oQKV + M1, CC, CC);
    wtrans_kernel<<<dim3(32, 32), 256, 0, stream>>>(sa_wv + wofs, wT + oQKV + 2 * M1, CC, CC);
    wtrans_kernel<<<dim3(32, 32), 256, 0, stream>>>(sa_wo + wofs, wT + oWO, CC, CC);
    wtrans_kernel<<<dim3(32, 32), 256, 0, stream>>>(ca_wq + wofs, wT + oCQ, CC, CC);
    wtrans_kernel<<<dim3(32, 32), 256, 0, stream>>>(ca_wk + wofs, wT + oCKV, CC, CC);
    wtrans_kernel<<<dim3(32, 32), 256, 0, stream>>>(ca_wv + wofs, wT + oCKV + M1, CC, CC);
    wtrans_kernel<<<dim3(32, 32), 256, 0, stream>>>(ca_wo + wofs, wT + oCWO, CC, CC);
    wtrans_kernel<<<dim3(128, 32), 256, 0, stream>>>(fc_w + mofs, wT + oFC, CC, DFF_);
    wtrans_kernel<<<dim3(32, 128), 256, 0, stream>>>(pr_w + mofs, wT + oPR, DFF_, CC);
    copyf_kernel<<<4, 256, 0, stream>>>(sa_bq + bofs, qkv_b, CC);
    copyf_kernel<<<4, 256, 0, stream>>>(sa_bk + bofs, qkv_b + CC, CC);
    copyf_kernel<<<4, 256, 0, stream>>>(sa_bv + bofs, qkv_b + 2 * CC, CC);
    copyf_kernel<<<4, 256, 0, stream>>>(ca_bk + bofs, cakv_b, CC);
    copyf_kernel<<<4, 256, 0, stream>>>(ca_bv + bofs, cakv_b + CC, CC);

    // ---- self attention ----
    ln_kernel<<<NTOK, 256, 0, stream>>>(x, ln1_w + bofs, ln1_b + bofs, nbf);
    gemm_bf16_kernel<0><<<dim3(24, 8), 256, 0, stream>>>(nbf, wT + oQKV, qkv_b, qkv, CC, 3072);
    gemm_kernel<true, 3, false><<<dim3(8, 8, 32), 256, 0, stream>>>(
        qkv, qkv + CC, att, DH, 3072, 3072, TT, qB, qH, qB, qH, aB, aH);
    softmax_kernel<<<32 * TT, 256, 0, stream>>>(att);
    gemm_kernel<false, 0, true><<<dim3(1, 8, 32), 256, 0, stream>>>(
        att, qkv + 2 * CC, (float*)ybf, TT, TT, 3072, CC, aB, aH, qB, qH, yB, yH);
    gemm_bf16_kernel<1><<<dim3(8, 8), 256, 0, stream>>>(ybf, wT + oWO, sa_bo + bofs, x, CC, CC);

    // ---- cross attention (ln_1 reused; causal mask kept, as in reference) ----
    ln_kernel<<<NTOK, 256, 0, stream>>>(x, ln1_w + bofs, ln1_b + bofs, nbf);
    gemm_bf16_kernel<0><<<dim3(8, 8), 256, 0, stream>>>(nbf, wT + oCQ, ca_bq + bofs, qkv, CC, 3072);
    gemm_bf16_kernel<0><<<dim3(16, 8), 256, 0, stream>>>(xabf, wT + oCKV, cakv_b, qkv + CC, CC, 3072);
    gemm_kernel<true, 3, false><<<dim3(8, 8, 32), 256, 0, stream>>>(
        qkv, qkv + CC, att, DH, 3072, 3072, TT, qB, qH, qB, qH, aB, aH);
    softmax_kernel<<<32 * TT, 256, 0, stream>>>(att);
    gemm_kernel<false, 0, true><<<dim3(1, 8, 32), 256, 0, stream>>>(
        att, qkv + 2 * CC, (float*)ybf, TT, TT, 3072, CC, aB, aH, qB, qH, yB, yH);
    gemm_bf16_kernel<1><<<dim3(8, 8), 256, 0, stream>>>(ybf, wT + oCWO, ca_bo + bofs, x, CC, CC);

    // ---- MLP ----
    ln_kernel<<<NTOK, 256, 0, stream>>>(x, ln2_w + bofs, ln2_b + bofs, nbf);
    gemm_bf16_kernel<2><<<dim3(32, 8), 256, 0, stream>>>(
        nbf, wT + oFC, fc_b + (size_t)l * DFF_, (float*)hmbf, CC, DFF_);
    gemm_bf16_kernel<1><<<dim3(8, 8), 256, 0, stream>>>(hmbf, wT + oPR, pr_b + bofs, x, DFF_, CC);
  }

  // ---- final LN + tied lm_head (n @ wte^T), wte already [N,K] ----
  ln_kernel<<<NTOK, 256, 0, stream>>>(x, lnf_w, lnf_b, nbf);
  gemm_bf16_kernel<0><<<dim3(250, 8), 256, 0, stream>>>(nbf, wtebf, nullptr, (float*)d_out, CC, VV);
}

// Round 6
// 2342.287 us; speedup vs baseline: 3.3083x; 1.2701x over previous
//
#include <hip/hip_runtime.h>
#include <math.h>

#define CC   1024
#define HH   16
#define DH   64
#define TT   512
#define NTOK 1024     // B*T
#define DFF_ 4096
#define VV   32000
#define QKSCALE 0.125f   // 1/sqrt(64)

typedef unsigned short u16;
typedef __attribute__((ext_vector_type(8))) short short8;
typedef __attribute__((ext_vector_type(4))) float f32x4;

__device__ __forceinline__ u16 f2bf(float f) {   // RNE fp32->bf16
  union { float f; unsigned u; } v; v.f = f;
  unsigned r = v.u + 0x7FFFu + ((v.u >> 16) & 1u);
  return (u16)(r >> 16);
}
__device__ __forceinline__ float gelu_f(float h) {
  return 0.5f * h * (1.0f + tanhf(0.7978845608028654f * (h + 0.044715f * h * h * h)));
}

// async global->LDS, 16B per lane; dest = wave-uniform base + lane*16
#define GLD16(gp, lp) __builtin_amdgcn_global_load_lds( \
    (const __attribute__((address_space(1))) void*)(gp), \
    (__attribute__((address_space(3))) void*)(lp), 16, 0, 0)

#define MFMA(a, b, c) __builtin_amdgcn_mfma_f32_16x16x32_bf16(a, b, c, 0, 0, 0)

// ---------------- embedding ----------------------------------------------
__global__ __launch_bounds__(256) void embed_kernel(
    const int* __restrict__ idx, const float* __restrict__ wte,
    const float* __restrict__ wpe, float* __restrict__ x) {
  int row = blockIdx.x;
  int t = row & (TT - 1);
  int id = idx[row];
  const float4* a = (const float4*)(wte + (size_t)id * CC);
  const float4* p = (const float4*)(wpe + (size_t)t * CC);
  float4* o = (float4*)(x + (size_t)row * CC);
  int c = threadIdx.x;
  float4 va = a[c], vp = p[c];
  float4 ov;
  ov.x = va.x + vp.x; ov.y = va.y + vp.y; ov.z = va.z + vp.z; ov.w = va.w + vp.w;
  o[c] = ov;
}

// ---------------- layernorm (fp32 in -> bf16 out) ------------------------
__global__ __launch_bounds__(256) void ln_kernel(
    const float* __restrict__ x, const float* __restrict__ w,
    const float* __restrict__ b, u16* __restrict__ out) {
  int row = blockIdx.x, tid = threadIdx.x;
  float4 v = ((const float4*)(x + (size_t)row * CC))[tid];
  float s  = v.x + v.y + v.z + v.w;
  float sq = fmaf(v.x, v.x, fmaf(v.y, v.y, fmaf(v.z, v.z, v.w * v.w)));
  for (int o = 32; o > 0; o >>= 1) { s += __shfl_down(s, o); sq += __shfl_down(sq, o); }
  __shared__ float rs[4], rq[4];
  int wid = tid >> 6, lane = tid & 63;
  if (lane == 0) { rs[wid] = s; rq[wid] = sq; }
  __syncthreads();
  s  = rs[0] + rs[1] + rs[2] + rs[3];
  sq = rq[0] + rq[1] + rq[2] + rq[3];
  float mean = s * (1.0f / CC);
  float var  = sq * (1.0f / CC) - mean * mean;
  float rstd = 1.0f / sqrtf(var + 1e-5f);
  float4 wv = ((const float4*)w)[tid];
  float4 bv = ((const float4*)b)[tid];
  ushort4 o;
  o.x = f2bf((v.x - mean) * rstd * wv.x + bv.x);
  o.y = f2bf((v.y - mean) * rstd * wv.y + bv.y);
  o.z = f2bf((v.z - mean) * rstd * wv.z + bv.z);
  o.w = f2bf((v.w - mean) * rstd * wv.w + bv.w);
  ((ushort4*)(out + (size_t)row * CC))[tid] = o;
}

// ---------------- weight transpose+convert: w[K,N] f32 -> wt[N,K] bf16 ---
__global__ __launch_bounds__(256) void wtrans_kernel(
    const float* __restrict__ w, u16* __restrict__ wt, int Kd, int Nd) {
  __shared__ float t[32][33];
  int bx = blockIdx.x * 32, by = blockIdx.y * 32;
  int c = threadIdx.x & 31, r = threadIdx.x >> 5;
#pragma unroll
  for (int i = 0; i < 4; ++i)
    t[r + i * 8][c] = w[(size_t)(by + r + i * 8) * Nd + bx + c];
  __syncthreads();
#pragma unroll
  for (int i = 0; i < 4; ++i)
    wt[(size_t)(bx + r + i * 8) * Kd + by + c] = f2bf(t[c][r + i * 8]);
}

// ---------------- elementwise f32 -> bf16 --------------------------------
__global__ __launch_bounds__(256) void convbf_kernel(
    const float* __restrict__ in, u16* __restrict__ out, int n4) {
  int i = blockIdx.x * 256 + threadIdx.x;
  if (i < n4) {
    float4 v = ((const float4*)in)[i];
    ushort4 o; o.x = f2bf(v.x); o.y = f2bf(v.y); o.z = f2bf(v.z); o.w = f2bf(v.w);
    ((ushort4*)out)[i] = o;
  }
}

// ---------------- small f32 copy (bias concat) ---------------------------
__global__ __launch_bounds__(256) void copyf_kernel(
    const float* __restrict__ s, float* __restrict__ d, int n) {
  int i = blockIdx.x * 256 + threadIdx.x;
  if (i < n) d[i] = s[i];
}

// ---------------- bf16 MFMA GEMM, BK=64, XOR-swizzled LDS ----------------
// C[M,N](ldc) = epi(A[M,K] @ B^T + bias);  A[M,K], B[N,K] bf16 row-major.
// 128x128 tile, 4 waves of 64x64.
// EPI: 0=store f32(+bias), 1=f32 +=(+bias) residual, 2=bf16 gelu(+bias),
//      4=bf16 per-head scatter (Cm = qkv base u16*; whichbase selects q/k/v)
// SWAP: blockIdx.x indexes rows (lm_head L2 reuse of B panels)
template <int EPI, bool SWAP>
__global__ __launch_bounds__(256) void gemm_bf16_kernel(
    const u16* __restrict__ A, const u16* __restrict__ B,
    const float* __restrict__ bias, float* __restrict__ Cm,
    int K, int ldc, int whichbase) {
  __shared__ u16 As[128 * 64];
  __shared__ u16 Bs[128 * 64];
  int tid = threadIdx.x;
  int lane = tid & 63, wave = tid >> 6;
  int wr = wave >> 1, wc = wave & 1;
  int row0 = (SWAP ? blockIdx.x : blockIdx.y) * 128;
  int col0 = (SWAP ? blockIdx.y : blockIdx.x) * 128;
  f32x4 acc[4][4];
#pragma unroll
  for (int m = 0; m < 4; ++m)
#pragma unroll
    for (int n = 0; n < 4; ++n) acc[m][n] = (f32x4){0.f, 0.f, 0.f, 0.f};

  int srow = tid >> 3;                       // staging row within pass
  int sblk = (tid & 7) ^ ((tid >> 3) & 7);   // pre-swizzled source 16B-blk
  const u16* Ab = A + (size_t)row0 * K;
  const u16* Bb = B + (size_t)col0 * K;
  int arow = wr * 64 + (lane & 15);
  int brow = wc * 64 + (lane & 15);
  int g8 = lane >> 4;

  for (int k0 = 0; k0 < K; k0 += 64) {
#pragma unroll
    for (int p = 0; p < 4; ++p)
      GLD16(Ab + (size_t)(p * 32 + srow) * K + k0 + sblk * 8,
            &As[p * 2048 + wave * 512]);
#pragma unroll
    for (int p = 0; p < 4; ++p)
      GLD16(Bb + (size_t)(p * 32 + srow) * K + k0 + sblk * 8,
            &Bs[p * 2048 + wave * 512]);
    __syncthreads();
#pragma unroll
    for (int ks = 0; ks < 2; ++ks) {
      short8 af[4], bg[4];
#pragma unroll
      for (int m = 0; m < 4; ++m) {
        int row = arow + m * 16;
        af[m] = *(const short8*)&As[row * 64 + (((ks * 4 + g8) ^ (row & 7)) << 3)];
      }
#pragma unroll
      for (int n = 0; n < 4; ++n) {
        int row = brow + n * 16;
        bg[n] = *(const short8*)&Bs[row * 64 + (((ks * 4 + g8) ^ (row & 7)) << 3)];
      }
#pragma unroll
      for (int m = 0; m < 4; ++m)
#pragma unroll
        for (int n = 0; n < 4; ++n)
          acc[m][n] = MFMA(af[m], bg[n], acc[m][n]);
    }
    __syncthreads();
  }

  float bj[4];
#pragma unroll
  for (int n = 0; n < 4; ++n)
    bj[n] = bias ? bias[col0 + wc * 64 + n * 16 + (lane & 15)] : 0.0f;
  int r0 = row0 + wr * 64 + g8 * 4;
  int c0 = col0 + wc * 64 + (lane & 15);

  if (EPI == 4) {
    // scatter to per-head layouts: q/k [bh][t][d], v [bh][d][t]
    u16* qb = (u16*)Cm;
#pragma unroll
    for (int m = 0; m < 4; ++m)
#pragma unroll
      for (int n = 0; n < 4; ++n) {
        int j = c0 + n * 16;
        int which = whichbase + (j >> 10);
        int h = (j & 1023) >> 6, d = j & 63;
        int trow0 = r0 + m * 16;
        int b = trow0 >> 9, t0 = trow0 & 511;
        int bh = b * 16 + h;
        u16 vals[4];
#pragma unroll
        for (int r = 0; r < 4; ++r) vals[r] = f2bf(acc[m][n][r] + bj[n]);
        if (which < 2) {
          u16* dst = qb + (size_t)which * 1048576 + (size_t)bh * 32768 + (size_t)t0 * 64 + d;
#pragma unroll
          for (int r = 0; r < 4; ++r) dst[(size_t)r * 64] = vals[r];
        } else {
          u16* dst = qb + 2 * 1048576 + (size_t)bh * 32768 + (size_t)d * 512 + t0;
          *(ushort4*)dst = *(ushort4*)vals;
        }
      }
    return;
  }

  u16* Cb = (u16*)Cm;
#pragma unroll
  for (int m = 0; m < 4; ++m)
#pragma unroll
    for (int n = 0; n < 4; ++n)
#pragma unroll
      for (int r = 0; r < 4; ++r) {
        size_t off = (size_t)(r0 + m * 16 + r) * ldc + c0 + n * 16;
        float v = acc[m][n][r] + bj[n];
        if (EPI == 0) Cm[off] = v;
        else if (EPI == 1) Cm[off] += v;
        else if (EPI == 2) Cb[off] = f2bf(gelu_f(v));
      }
}

// ---------------- fused flash attention (causal, incl. cross per ref) ----
// q,k: [32 bh][512 t][64 d] bf16;  v: [32 bh][64 d][512 t] bf16
// y: [1024 tok][1024 C] bf16.  Grid (16 q-tiles, 32 bh), 256 threads.
__global__ __launch_bounds__(256) void attn_kernel(
    const u16* __restrict__ qh, const u16* __restrict__ kh,
    const u16* __restrict__ vt, u16* __restrict__ y) {
  __shared__ u16 P[32 * 512];             // swizzled probs
  __shared__ float smax[4][32], ssum[4][32];
  int tid = threadIdx.x, lane = tid & 63, w = tid >> 6;
  int bx = blockIdx.x, bh = blockIdx.y;
  int q0 = bx * 32;
  int b = bh >> 4, h = bh & 15;
  const u16* qb = qh + (size_t)bh * 32768;
  const u16* kb = kh + (size_t)bh * 32768;
  const u16* vb = vt + (size_t)bh * 32768;
  int g = lane >> 4, c = lane & 15;

  // Q fragments (A-operand): rows q0+rt*16+c, k = ks*32 + g*8
  short8 a[2][2];
#pragma unroll
  for (int rt = 0; rt < 2; ++rt)
#pragma unroll
    for (int ks = 0; ks < 2; ++ks)
      a[rt][ks] = *(const short8*)(qb + (size_t)(q0 + rt * 16 + c) * 64 + ks * 32 + g * 8);

  // ---- S = Q @ K^T over this wave's 128-col slice (causal tile skip) ----
  int lim = q0 + 31;
  int nct = (lim - w * 128) / 16 + 1;           // #16-col tiles to compute
  if (nct > 8) nct = 8;
  if (nct < 0) nct = 0;
  f32x4 s[2][8];
#pragma unroll
  for (int rt = 0; rt < 2; ++rt)
#pragma unroll
    for (int ct = 0; ct < 8; ++ct) s[rt][ct] = (f32x4){0.f, 0.f, 0.f, 0.f};
  for (int ct = 0; ct < nct; ++ct) {
    int n0 = w * 128 + ct * 16;
#pragma unroll
    for (int ks = 0; ks < 2; ++ks) {
      short8 bf = *(const short8*)(kb + (size_t)(n0 + c) * 64 + ks * 32 + g * 8);
      s[0][ct] = MFMA(a[0][ks], bf, s[0][ct]);
      s[1][ct] = MFMA(a[1][ks], bf, s[1][ct]);
    }
  }

  // ---- scale + causal mask + wave-slice row max ----
  float mx[2][4];
#pragma unroll
  for (int rt = 0; rt < 2; ++rt)
#pragma unroll
    for (int r = 0; r < 4; ++r) mx[rt][r] = -1e30f;
  for (int ct = 0; ct < nct; ++ct) {
    int col = w * 128 + ct * 16 + c;
#pragma unroll
    for (int rt = 0; rt < 2; ++rt)
#pragma unroll
      for (int r = 0; r < 4; ++r) {
        int trow = q0 + rt * 16 + g * 4 + r;
        float v = s[rt][ct][r] * QKSCALE;
        if (col > trow) v = -1e30f;
        s[rt][ct][r] = v;
        mx[rt][r] = fmaxf(mx[rt][r], v);
      }
  }
#pragma unroll
  for (int off = 1; off < 16; off <<= 1)
#pragma unroll
    for (int rt = 0; rt < 2; ++rt)
#pragma unroll
      for (int r = 0; r < 4; ++r) mx[rt][r] = fmaxf(mx[rt][r], __shfl_xor(mx[rt][r], off));
  if (c == 0)
#pragma unroll
    for (int rt = 0; rt < 2; ++rt)
#pragma unroll
      for (int r = 0; r < 4; ++r) smax[w][rt * 16 + g * 4 + r] = mx[rt][r];
  __syncthreads();

  // ---- global row max, p = exp, P->LDS (swizzled bf16), row sums ----
  float m_[2][4], sum[2][4];
#pragma unroll
  for (int rt = 0; rt < 2; ++rt)
#pragma unroll
    for (int r = 0; r < 4; ++r) {
      int row = rt * 16 + g * 4 + r;
      m_[rt][r] = fmaxf(fmaxf(smax[0][row], smax[1][row]), fmaxf(smax[2][row], smax[3][row]));
      sum[rt][r] = 0.f;
    }
  for (int ct = 0; ct < nct; ++ct) {
    int col = w * 128 + ct * 16 + c;
    int blk = col >> 3, cl = col & 7;
#pragma unroll
    for (int rt = 0; rt < 2; ++rt)
#pragma unroll
      for (int r = 0; r < 4; ++r) {
        float p = __expf(s[rt][ct][r] - m_[rt][r]);
        sum[rt][r] += p;
        int row = rt * 16 + g * 4 + r;
        int hsh = (row ^ (row >> 2)) & 7;
        P[row * 512 + ((blk ^ hsh) << 3) + cl] = f2bf(p);
      }
  }
#pragma unroll
  for (int off = 1; off < 16; off <<= 1)
#pragma unroll
    for (int rt = 0; rt < 2; ++rt)
#pragma unroll
      for (int r = 0; r < 4; ++r) sum[rt][r] += __shfl_xor(sum[rt][r], off);
  if (c == 0)
#pragma unroll
    for (int rt = 0; rt < 2; ++rt)
#pragma unroll
      for (int r = 0; r < 4; ++r) ssum[w][rt * 16 + g * 4 + r] = sum[rt][r];
  __syncthreads();

  float li[2][4];
#pragma unroll
  for (int rt = 0; rt < 2; ++rt)
#pragma unroll
    for (int r = 0; r < 4; ++r) {
      int row = rt * 16 + g * 4 + r;
      li[rt][r] = 1.0f / (ssum[0][row] + ssum[1][row] + ssum[2][row] + ssum[3][row]);
    }

  // ---- O = P @ V : wave (rt2, nh) owns 16 rows x 32 cols ----
  int rt2 = w >> 1, nh = w & 1;
  f32x4 o[2];
  o[0] = (f32x4){0.f, 0.f, 0.f, 0.f};
  o[1] = (f32x4){0.f, 0.f, 0.f, 0.f};
  int nks = bx + 1;
  int prow = rt2 * 16 + c;
  int phsh = (prow ^ (prow >> 2)) & 7;
  for (int ks = 0; ks < nks; ++ks) {
    short8 pa = *(const short8*)&P[prow * 512 + (((ks * 4 + g) ^ phsh) << 3)];
#pragma unroll
    for (int nt = 0; nt < 2; ++nt) {
      int d = nh * 32 + nt * 16 + c;
      short8 vf = *(const short8*)(vb + (size_t)d * 512 + ks * 32 + g * 8);
      o[nt] = MFMA(pa, vf, o[nt]);
    }
  }
#pragma unroll
  for (int nt = 0; nt < 2; ++nt)
#pragma unroll
    for (int r = 0; r < 4; ++r) {
      int trow = q0 + rt2 * 16 + g * 4 + r;
      float val = o[nt][r] * li[rt2][r];
      y[(size_t)(b * 512 + trow) * 1024 + h * 64 + nh * 32 + nt * 16 + c] = f2bf(val);
    }
}

// ---------------- launch ---------------------------------------------------
extern "C" void kernel_launch(void* const* d_in, const int* in_sizes, int n_in,
                              void* d_out, int out_size, void* d_ws, size_t ws_size,
                              hipStream_t stream) {
  const int*   idx   = (const int*)d_in[0];
  const float* xa    = (const float*)d_in[1];
  const float* wte   = (const float*)d_in[2];
  const float* wpe   = (const float*)d_in[3];
  const float* ln1_w = (const float*)d_in[4];
  const float* ln1_b = (const float*)d_in[5];
  const float* sa_wq = (const float*)d_in[6];
  const float* sa_bq = (const float*)d_in[7];
  const float* sa_wk = (const float*)d_in[8];
  const float* sa_bk = (const float*)d_in[9];
  const float* sa_wv = (const float*)d_in[10];
  const float* sa_bv = (const float*)d_in[11];
  const float* sa_wo = (const float*)d_in[12];
  const float* sa_bo = (const float*)d_in[13];
  const float* ca_wq = (const float*)d_in[14];
  const float* ca_bq = (const float*)d_in[15];
  const float* ca_wk = (const float*)d_in[16];
  const float* ca_bk = (const float*)d_in[17];
  const float* ca_wv = (const float*)d_in[18];
  const float* ca_bv = (const float*)d_in[19];
  const float* ca_wo = (const float*)d_in[20];
  const float* ca_bo = (const float*)d_in[21];
  const float* ln2_w = (const float*)d_in[22];
  const float* ln2_b = (const float*)d_in[23];
  const float* fc_w  = (const float*)d_in[24];
  const float* fc_b  = (const float*)d_in[25];
  const float* pr_w  = (const float*)d_in[26];
  const float* pr_b  = (const float*)d_in[27];
  const float* lnf_w = (const float*)d_in[28];
  const float* lnf_b = (const float*)d_in[29];

  const size_t M1 = 1048576;
  float* ws     = (float*)d_ws;
  float* x      = ws;                    // [1024,1024] f32
  float* qkv_b  = x + M1;                // [3072] (+pad)
  float* cakv_b = qkv_b + 4096;          // [2048]
  u16* qkvh  = (u16*)(cakv_b + 2048);    // q,k: [32][512][64]; v: [32][64][512]
  u16* nbf   = qkvh + 3 * M1;            // [1024,1024] bf16
  u16* ybf   = nbf + M1;                 // [1024,1024] bf16
  u16* hmbf  = ybf + M1;                 // [1024,4096] bf16
  u16* xabf  = hmbf + 4 * M1;            // [1024,1024] bf16
  u16* wtebf = xabf + M1;                // [32000,1024] bf16
  u16* wT    = wtebf + (size_t)VV * CC;  // 16M bf16 per-layer transposed weights

  const size_t oQKV = 0, oWO = 3 * M1, oCQ = 4 * M1, oCKV = 5 * M1,
               oCWO = 7 * M1, oFC = 8 * M1, oPR = 12 * M1;

  embed_kernel<<<NTOK, 256, 0, stream>>>(idx, wte, wpe, x);
  convbf_kernel<<<(VV * CC / 4 + 255) / 256, 256, 0, stream>>>(wte, wtebf, VV * CC / 4);
  convbf_kernel<<<(NTOK * CC / 4 + 255) / 256, 256, 0, stream>>>(xa, xabf, NTOK * CC / 4);

  for (int l = 0; l < 6; ++l) {
    size_t wofs = (size_t)l * CC * CC;
    size_t bofs = (size_t)l * CC;
    size_t mofs = (size_t)l * CC * DFF_;

    wtrans_kernel<<<dim3(32, 32), 256, 0, stream>>>(sa_wq + wofs, wT + oQKV, CC, CC);
    wtrans_kernel<<<dim3(32, 32), 256, 0, stream>>>(sa_wk + wofs, wT + oQKV + M1, CC, CC);
    wtrans_kernel<<<dim3(32, 32), 256, 0, stream>>>(sa_wv + wofs, wT + oQKV + 2 * M1, CC, CC);
    wtrans_kernel<<<dim3(32, 32), 256, 0, stream>>>(sa_wo + wofs, wT + oWO, CC, CC);
    wtrans_kernel<<<dim3(32, 32), 256, 0, stream>>>(ca_wq + wofs, wT + oCQ, CC, CC);
    wtrans_kernel<<<dim3(32, 32), 256, 0, stream>>>(ca_wk + wofs, wT + oCKV, CC, CC);
    wtrans_kernel<<<dim3(32, 32), 256, 0, stream>>>(ca_wv + wofs, wT + oCKV + M1, CC, CC);
    wtrans_kernel<<<dim3(32, 32), 256, 0, stream>>>(ca_wo + wofs, wT + oCWO, CC, CC);
    wtrans_kernel<<<dim3(128, 32), 256, 0, stream>>>(fc_w + mofs, wT + oFC, CC, DFF_);
    wtrans_kernel<<<dim3(32, 128), 256, 0, stream>>>(pr_w + mofs, wT + oPR, DFF_, CC);
    copyf_kernel<<<4, 256, 0, stream>>>(sa_bq + bofs, qkv_b, CC);
    copyf_kernel<<<4, 256, 0, stream>>>(sa_bk + bofs, qkv_b + CC, CC);
    copyf_kernel<<<4, 256, 0, stream>>>(sa_bv + bofs, qkv_b + 2 * CC, CC);
    copyf_kernel<<<4, 256, 0, stream>>>(ca_bk + bofs, cakv_b, CC);
    copyf_kernel<<<4, 256, 0, stream>>>(ca_bv + bofs, cakv_b + CC, CC);

    // ---- self attention ----
    ln_kernel<<<NTOK, 256, 0, stream>>>(x, ln1_w + bofs, ln1_b + bofs, nbf);
    gemm_bf16_kernel<4, false><<<dim3(24, 8), 256, 0, stream>>>(
        nbf, wT + oQKV, qkv_b, (float*)qkvh, CC, 0, 0);
    attn_kernel<<<dim3(16, 32), 256, 0, stream>>>(qkvh, qkvh + M1, qkvh + 2 * M1, ybf);
    gemm_bf16_kernel<1, false><<<dim3(8, 8), 256, 0, stream>>>(
        ybf, wT + oWO, sa_bo + bofs, x, CC, CC, 0);

    // ---- cross attention (ln_1 reused; causal mask kept, as in reference) ----
    ln_kernel<<<NTOK, 256, 0, stream>>>(x, ln1_w + bofs, ln1_b + bofs, nbf);
    gemm_bf16_kernel<4, false><<<dim3(8, 8), 256, 0, stream>>>(
        nbf, wT + oCQ, ca_bq + bofs, (float*)qkvh, CC, 0, 0);
    gemm_bf16_kernel<4, false><<<dim3(16, 8), 256, 0, stream>>>(
        xabf, wT + oCKV, cakv_b, (float*)qkvh, CC, 0, 1);
    attn_kernel<<<dim3(16, 32), 256, 0, stream>>>(qkvh, qkvh + M1, qkvh + 2 * M1, ybf);
    gemm_bf16_kernel<1, false><<<dim3(8, 8), 256, 0, stream>>>(
        ybf, wT + oCWO, ca_bo + bofs, x, CC, CC, 0);

    // ---- MLP ----
    ln_kernel<<<NTOK, 256, 0, stream>>>(x, ln2_w + bofs, ln2_b + bofs, nbf);
    gemm_bf16_kernel<2, false><<<dim3(32, 8), 256, 0, stream>>>(
        nbf, wT + oFC, fc_b + (size_t)l * DFF_, (float*)hmbf, CC, DFF_, 0);
    gemm_bf16_kernel<1, false><<<dim3(8, 8), 256, 0, stream>>>(
        hmbf, wT + oPR, pr_b + bofs, x, DFF_, CC, 0);
  }

  // ---- final LN + tied lm_head (n @ wte^T), SWAP grid for B-panel L2 reuse
  ln_kernel<<<NTOK, 256, 0, stream>>>(x, lnf_w, lnf_b, nbf);
  gemm_bf16_kernel<0, true><<<dim3(8, 250), 256, 0, stream>>>(
      nbf, wtebf, nullptr, (float*)d_out, CC, VV, 0);
}

// Round 7
// 2268.455 us; speedup vs baseline: 3.4160x; 1.0325x over previous
//
#include <hip/hip_runtime.h>
#include <math.h>

#define CC   1024
#define HH   16
#define DH   64
#define TT   512
#define NTOK 1024     // B*T
#define DFF_ 4096
#define VV   32000
#define QKSCALE 0.125f   // 1/sqrt(64)

typedef unsigned short u16;
typedef __attribute__((ext_vector_type(8))) short short8;
typedef __attribute__((ext_vector_type(4))) float f32x4;

__device__ __forceinline__ u16 f2bf(float f) {   // RNE fp32->bf16
  union { float f; unsigned u; } v; v.f = f;
  unsigned r = v.u + 0x7FFFu + ((v.u >> 16) & 1u);
  return (u16)(r >> 16);
}
__device__ __forceinline__ float gelu_f(float h) {
  return 0.5f * h * (1.0f + tanhf(0.7978845608028654f * (h + 0.044715f * h * h * h)));
}

// async global->LDS, 16B per lane; dest = wave-uniform base + lane*16
#define GLD16(gp, lp) __builtin_amdgcn_global_load_lds( \
    (const __attribute__((address_space(1))) void*)(gp), \
    (__attribute__((address_space(3))) void*)(lp), 16, 0, 0)

#define MFMA(a, b, c) __builtin_amdgcn_mfma_f32_16x16x32_bf16(a, b, c, 0, 0, 0)

// ---------------- embedding ----------------------------------------------
__global__ __launch_bounds__(256) void embed_kernel(
    const int* __restrict__ idx, const float* __restrict__ wte,
    const float* __restrict__ wpe, float* __restrict__ x) {
  int row = blockIdx.x;
  int t = row & (TT - 1);
  int id = idx[row];
  const float4* a = (const float4*)(wte + (size_t)id * CC);
  const float4* p = (const float4*)(wpe + (size_t)t * CC);
  float4* o = (float4*)(x + (size_t)row * CC);
  int c = threadIdx.x;
  float4 va = a[c], vp = p[c];
  float4 ov;
  ov.x = va.x + vp.x; ov.y = va.y + vp.y; ov.z = va.z + vp.z; ov.w = va.w + vp.w;
  o[c] = ov;
}

// ---------------- layernorm (fp32 in -> bf16 out) ------------------------
__global__ __launch_bounds__(256) void ln_kernel(
    const float* __restrict__ x, const float* __restrict__ w,
    const float* __restrict__ b, u16* __restrict__ out) {
  int row = blockIdx.x, tid = threadIdx.x;
  float4 v = ((const float4*)(x + (size_t)row * CC))[tid];
  float s  = v.x + v.y + v.z + v.w;
  float sq = fmaf(v.x, v.x, fmaf(v.y, v.y, fmaf(v.z, v.z, v.w * v.w)));
  for (int o = 32; o > 0; o >>= 1) { s += __shfl_down(s, o); sq += __shfl_down(sq, o); }
  __shared__ float rs[4], rq[4];
  int wid = tid >> 6, lane = tid & 63;
  if (lane == 0) { rs[wid] = s; rq[wid] = sq; }
  __syncthreads();
  s  = rs[0] + rs[1] + rs[2] + rs[3];
  sq = rq[0] + rq[1] + rq[2] + rq[3];
  float mean = s * (1.0f / CC);
  float var  = sq * (1.0f / CC) - mean * mean;
  float rstd = 1.0f / sqrtf(var + 1e-5f);
  float4 wv = ((const float4*)w)[tid];
  float4 bv = ((const float4*)b)[tid];
  ushort4 o;
  o.x = f2bf((v.x - mean) * rstd * wv.x + bv.x);
  o.y = f2bf((v.y - mean) * rstd * wv.y + bv.y);
  o.z = f2bf((v.z - mean) * rstd * wv.z + bv.z);
  o.w = f2bf((v.w - mean) * rstd * wv.w + bv.w);
  ((ushort4*)(out + (size_t)row * CC))[tid] = o;
}

// ---------------- weight transpose: generic rect ---------------------------
__global__ __launch_bounds__(256) void wtrans_kernel(
    const float* __restrict__ w, u16* __restrict__ wt, int Kd, int Nd) {
  __shared__ float t[32][33];
  int bx = blockIdx.x * 32, by = blockIdx.y * 32;
  int c = threadIdx.x & 31, r = threadIdx.x >> 5;
#pragma unroll
  for (int i = 0; i < 4; ++i)
    t[r + i * 8][c] = w[(size_t)(by + r + i * 8) * Nd + bx + c];
  __syncthreads();
#pragma unroll
  for (int i = 0; i < 4; ++i)
    wt[(size_t)(bx + r + i * 8) * Kd + by + c] = f2bf(t[c][r + i * 8]);
}

// ---------------- fused 8x square (1024x1024) transpose, z selects src ----
__global__ __launch_bounds__(256) void wtrans8_kernel(
    const float* __restrict__ w0, const float* __restrict__ w1,
    const float* __restrict__ w2, const float* __restrict__ w3,
    const float* __restrict__ w4, const float* __restrict__ w5,
    const float* __restrict__ w6, const float* __restrict__ w7,
    u16* __restrict__ wt) {
  int z = blockIdx.z;
  const float* w = z == 0 ? w0 : z == 1 ? w1 : z == 2 ? w2 : z == 3 ? w3
                 : z == 4 ? w4 : z == 5 ? w5 : z == 6 ? w6 : w7;
  u16* dst = wt + (size_t)z * 1048576;
  __shared__ float t[32][33];
  int bx = blockIdx.x * 32, by = blockIdx.y * 32;
  int c = threadIdx.x & 31, r = threadIdx.x >> 5;
#pragma unroll
  for (int i = 0; i < 4; ++i)
    t[r + i * 8][c] = w[(size_t)(by + r + i * 8) * CC + bx + c];
  __syncthreads();
#pragma unroll
  for (int i = 0; i < 4; ++i)
    dst[(size_t)(bx + r + i * 8) * CC + by + c] = f2bf(t[c][r + i * 8]);
}

// ---------------- elementwise f32 -> bf16 --------------------------------
__global__ __launch_bounds__(256) void convbf_kernel(
    const float* __restrict__ in, u16* __restrict__ out, int n4) {
  int i = blockIdx.x * 256 + threadIdx.x;
  if (i < n4) {
    float4 v = ((const float4*)in)[i];
    ushort4 o; o.x = f2bf(v.x); o.y = f2bf(v.y); o.z = f2bf(v.z); o.w = f2bf(v.w);
    ((ushort4*)out)[i] = o;
  }
}

// ---------------- bf16 MFMA GEMM, BK=64, XOR-swizzled LDS ----------------
// C[M,N](ldc) = epi(A[M,K] @ B^T + bias);  A[M,K], B[N,K] bf16 row-major.
// 128x128 tile, 4 waves of 64x64.
// EPI: 0=store f32(+bias), 1=f32 +=(+bias) residual, 2=bf16 gelu(+bias),
//      4=bf16 per-head scatter (Cm = qkv base u16*; bias/bias2/bias3 per
//        1024-col chunk selected by whichbase + (col>>10))
// MODE: 0 = normal grid (x=cols, y=rows); 2 = lm_head 1D grid with
//       bijective XCD swizzle (2000 blocks = 8 row-blks x 250 col-panels)
template <int EPI, int MODE>
__global__ __launch_bounds__(256) void gemm_bf16_kernel(
    const u16* __restrict__ A, const u16* __restrict__ B,
    const float* __restrict__ bias, const float* __restrict__ bias2,
    const float* __restrict__ bias3, float* __restrict__ Cm,
    int K, int ldc, int whichbase) {
  __shared__ u16 As[128 * 64];
  __shared__ u16 Bs[128 * 64];
  int tid = threadIdx.x;
  int lane = tid & 63, wave = tid >> 6;
  int wr = wave >> 1, wc = wave & 1;
  int row0, col0;
  if (MODE == 2) {
    int id = blockIdx.x;                 // 0..1999
    int wg = (id & 7) * 250 + (id >> 3); // bijective: each XCD gets 250 wgs
    row0 = (wg & 7) * 128;               // 8 row-blocks cycle fastest
    col0 = (wg >> 3) * 128;              // ~31 contiguous col-panels per XCD
  } else {
    row0 = blockIdx.y * 128;
    col0 = blockIdx.x * 128;
  }
  f32x4 acc[4][4];
#pragma unroll
  for (int m = 0; m < 4; ++m)
#pragma unroll
    for (int n = 0; n < 4; ++n) acc[m][n] = (f32x4){0.f, 0.f, 0.f, 0.f};

  int srow = tid >> 3;                       // staging row within pass
  int sblk = (tid & 7) ^ ((tid >> 3) & 7);   // pre-swizzled source 16B-blk
  const u16* Ab = A + (size_t)row0 * K;
  const u16* Bb = B + (size_t)col0 * K;
  int arow = wr * 64 + (lane & 15);
  int brow = wc * 64 + (lane & 15);
  int g8 = lane >> 4;

  for (int k0 = 0; k0 < K; k0 += 64) {
#pragma unroll
    for (int p = 0; p < 4; ++p)
      GLD16(Ab + (size_t)(p * 32 + srow) * K + k0 + sblk * 8,
            &As[p * 2048 + wave * 512]);
#pragma unroll
    for (int p = 0; p < 4; ++p)
      GLD16(Bb + (size_t)(p * 32 + srow) * K + k0 + sblk * 8,
            &Bs[p * 2048 + wave * 512]);
    __syncthreads();
#pragma unroll
    for (int ks = 0; ks < 2; ++ks) {
      short8 af[4], bg[4];
#pragma unroll
      for (int m = 0; m < 4; ++m) {
        int row = arow + m * 16;
        af[m] = *(const short8*)&As[row * 64 + (((ks * 4 + g8) ^ (row & 7)) << 3)];
      }
#pragma unroll
      for (int n = 0; n < 4; ++n) {
        int row = brow + n * 16;
        bg[n] = *(const short8*)&Bs[row * 64 + (((ks * 4 + g8) ^ (row & 7)) << 3)];
      }
#pragma unroll
      for (int m = 0; m < 4; ++m)
#pragma unroll
        for (int n = 0; n < 4; ++n)
          acc[m][n] = MFMA(af[m], bg[n], acc[m][n]);
    }
    __syncthreads();
  }

  int r0 = row0 + wr * 64 + g8 * 4;
  int c0 = col0 + wc * 64 + (lane & 15);

  if (EPI == 4) {
    // scatter to per-head layouts: q/k [bh][t][d], v [bh][d][t]
    u16* qb = (u16*)Cm;
#pragma unroll
    for (int m = 0; m < 4; ++m)
#pragma unroll
      for (int n = 0; n < 4; ++n) {
        int j = c0 + n * 16;
        int which = whichbase + (j >> 10);
        const float* bp = (j >> 10) == 0 ? bias : ((j >> 10) == 1 ? bias2 : bias3);
        float bj = bp ? bp[j & 1023] : 0.0f;
        int h = (j & 1023) >> 6, d = j & 63;
        int trow0 = r0 + m * 16;
        int b = trow0 >> 9, t0 = trow0 & 511;
        int bh = b * 16 + h;
        u16 vals[4];
#pragma unroll
        for (int r = 0; r < 4; ++r) vals[r] = f2bf(acc[m][n][r] + bj);
        if (which < 2) {
          u16* dst = qb + (size_t)which * 1048576 + (size_t)bh * 32768 + (size_t)t0 * 64 + d;
#pragma unroll
          for (int r = 0; r < 4; ++r) dst[(size_t)r * 64] = vals[r];
        } else {
          u16* dst = qb + 2 * 1048576 + (size_t)bh * 32768 + (size_t)d * 512 + t0;
          *(ushort4*)dst = *(ushort4*)vals;
        }
      }
    return;
  }

  float bj[4];
#pragma unroll
  for (int n = 0; n < 4; ++n)
    bj[n] = bias ? bias[col0 + wc * 64 + n * 16 + (lane & 15)] : 0.0f;
  u16* Cb = (u16*)Cm;
#pragma unroll
  for (int m = 0; m < 4; ++m)
#pragma unroll
    for (int n = 0; n < 4; ++n)
#pragma unroll
      for (int r = 0; r < 4; ++r) {
        size_t off = (size_t)(r0 + m * 16 + r) * ldc + c0 + n * 16;
        float v = acc[m][n][r] + bj[n];
        if (EPI == 0) Cm[off] = v;
        else if (EPI == 1) Cm[off] += v;
        else if (EPI == 2) Cb[off] = f2bf(gelu_f(v));
      }
}

// ---------------- fused flash attention (causal, incl. cross per ref) ----
// q,k: [32 bh][512 t][64 d] bf16;  v: [32 bh][64 d][512 t] bf16
// y: [1024 tok][1024 C] bf16.  Grid (16 q-tiles, 32 bh), 256 threads.
__global__ __launch_bounds__(256) void attn_kernel(
    const u16* __restrict__ qh, const u16* __restrict__ kh,
    const u16* __restrict__ vt, u16* __restrict__ y) {
  __shared__ u16 P[32 * 512];             // swizzled probs
  __shared__ float smax[4][32], ssum[4][32];
  int tid = threadIdx.x, lane = tid & 63, w = tid >> 6;
  int bx = blockIdx.x, bh = blockIdx.y;
  int q0 = bx * 32;
  int b = bh >> 4, h = bh & 15;
  const u16* qb = qh + (size_t)bh * 32768;
  const u16* kb = kh + (size_t)bh * 32768;
  const u16* vb = vt + (size_t)bh * 32768;
  int g = lane >> 4, c = lane & 15;

  short8 a[2][2];
#pragma unroll
  for (int rt = 0; rt < 2; ++rt)
#pragma unroll
    for (int ks = 0; ks < 2; ++ks)
      a[rt][ks] = *(const short8*)(qb + (size_t)(q0 + rt * 16 + c) * 64 + ks * 32 + g * 8);

  int lim = q0 + 31;
  int nct = (lim - w * 128) / 16 + 1;
  if (nct > 8) nct = 8;
  if (nct < 0) nct = 0;
  f32x4 s[2][8];
#pragma unroll
  for (int rt = 0; rt < 2; ++rt)
#pragma unroll
    for (int ct = 0; ct < 8; ++ct) s[rt][ct] = (f32x4){0.f, 0.f, 0.f, 0.f};
  for (int ct = 0; ct < nct; ++ct) {
    int n0 = w * 128 + ct * 16;
#pragma unroll
    for (int ks = 0; ks < 2; ++ks) {
      short8 bf = *(const short8*)(kb + (size_t)(n0 + c) * 64 + ks * 32 + g * 8);
      s[0][ct] = MFMA(a[0][ks], bf, s[0][ct]);
      s[1][ct] = MFMA(a[1][ks], bf, s[1][ct]);
    }
  }

  float mx[2][4];
#pragma unroll
  for (int rt = 0; rt < 2; ++rt)
#pragma unroll
    for (int r = 0; r < 4; ++r) mx[rt][r] = -1e30f;
  for (int ct = 0; ct < nct; ++ct) {
    int col = w * 128 + ct * 16 + c;
#pragma unroll
    for (int rt = 0; rt < 2; ++rt)
#pragma unroll
      for (int r = 0; r < 4; ++r) {
        int trow = q0 + rt * 16 + g * 4 + r;
        float v = s[rt][ct][r] * QKSCALE;
        if (col > trow) v = -1e30f;
        s[rt][ct][r] = v;
        mx[rt][r] = fmaxf(mx[rt][r], v);
      }
  }
#pragma unroll
  for (int off = 1; off < 16; off <<= 1)
#pragma unroll
    for (int rt = 0; rt < 2; ++rt)
#pragma unroll
      for (int r = 0; r < 4; ++r) mx[rt][r] = fmaxf(mx[rt][r], __shfl_xor(mx[rt][r], off));
  if (c == 0)
#pragma unroll
    for (int rt = 0; rt < 2; ++rt)
#pragma unroll
      for (int r = 0; r < 4; ++r) smax[w][rt * 16 + g * 4 + r] = mx[rt][r];
  __syncthreads();

  float m_[2][4], sum[2][4];
#pragma unroll
  for (int rt = 0; rt < 2; ++rt)
#pragma unroll
    for (int r = 0; r < 4; ++r) {
      int row = rt * 16 + g * 4 + r;
      m_[rt][r] = fmaxf(fmaxf(smax[0][row], smax[1][row]), fmaxf(smax[2][row], smax[3][row]));
      sum[rt][r] = 0.f;
    }
  for (int ct = 0; ct < nct; ++ct) {
    int col = w * 128 + ct * 16 + c;
    int blk = col >> 3, cl = col & 7;
#pragma unroll
    for (int rt = 0; rt < 2; ++rt)
#pragma unroll
      for (int r = 0; r < 4; ++r) {
        float p = __expf(s[rt][ct][r] - m_[rt][r]);
        sum[rt][r] += p;
        int row = rt * 16 + g * 4 + r;
        int hsh = (row ^ (row >> 2)) & 7;
        P[row * 512 + ((blk ^ hsh) << 3) + cl] = f2bf(p);
      }
  }
#pragma unroll
  for (int off = 1; off < 16; off <<= 1)
#pragma unroll
    for (int rt = 0; rt < 2; ++rt)
#pragma unroll
      for (int r = 0; r < 4; ++r) sum[rt][r] += __shfl_xor(sum[rt][r], off);
  if (c == 0)
#pragma unroll
    for (int rt = 0; rt < 2; ++rt)
#pragma unroll
      for (int r = 0; r < 4; ++r) ssum[w][rt * 16 + g * 4 + r] = sum[rt][r];
  __syncthreads();

  float li[2][4];
#pragma unroll
  for (int rt = 0; rt < 2; ++rt)
#pragma unroll
    for (int r = 0; r < 4; ++r) {
      int row = rt * 16 + g * 4 + r;
      li[rt][r] = 1.0f / (ssum[0][row] + ssum[1][row] + ssum[2][row] + ssum[3][row]);
    }

  int rt2 = w >> 1, nh = w & 1;
  f32x4 o[2];
  o[0] = (f32x4){0.f, 0.f, 0.f, 0.f};
  o[1] = (f32x4){0.f, 0.f, 0.f, 0.f};
  int nks = bx + 1;
  int prow = rt2 * 16 + c;
  int phsh = (prow ^ (prow >> 2)) & 7;
  for (int ks = 0; ks < nks; ++ks) {
    short8 pa = *(const short8*)&P[prow * 512 + (((ks * 4 + g) ^ phsh) << 3)];
#pragma unroll
    for (int nt = 0; nt < 2; ++nt) {
      int d = nh * 32 + nt * 16 + c;
      short8 vf = *(const short8*)(vb + (size_t)d * 512 + ks * 32 + g * 8);
      o[nt] = MFMA(pa, vf, o[nt]);
    }
  }
#pragma unroll
  for (int nt = 0; nt < 2; ++nt)
#pragma unroll
    for (int r = 0; r < 4; ++r) {
      int trow = q0 + rt2 * 16 + g * 4 + r;
      float val = o[nt][r] * li[rt2][r];
      y[(size_t)(b * 512 + trow) * 1024 + h * 64 + nh * 32 + nt * 16 + c] = f2bf(val);
    }
}

// ---------------- launch ---------------------------------------------------
extern "C" void kernel_launch(void* const* d_in, const int* in_sizes, int n_in,
                              void* d_out, int out_size, void* d_ws, size_t ws_size,
                              hipStream_t stream) {
  const int*   idx   = (const int*)d_in[0];
  const float* xa    = (const float*)d_in[1];
  const float* wte   = (const float*)d_in[2];
  const float* wpe   = (const float*)d_in[3];
  const float* ln1_w = (const float*)d_in[4];
  const float* ln1_b = (const float*)d_in[5];
  const float* sa_wq = (const float*)d_in[6];
  const float* sa_bq = (const float*)d_in[7];
  const float* sa_wk = (const float*)d_in[8];
  const float* sa_bk = (const float*)d_in[9];
  const float* sa_wv = (const float*)d_in[10];
  const float* sa_bv = (const float*)d_in[11];
  const float* sa_wo = (const float*)d_in[12];
  const float* sa_bo = (const float*)d_in[13];
  const float* ca_wq = (const float*)d_in[14];
  const float* ca_bq = (const float*)d_in[15];
  const float* ca_wk = (const float*)d_in[16];
  const float* ca_bk = (const float*)d_in[17];
  const float* ca_wv = (const float*)d_in[18];
  const float* ca_bv = (const float*)d_in[19];
  const float* ca_wo = (const float*)d_in[20];
  const float* ca_bo = (const float*)d_in[21];
  const float* ln2_w = (const float*)d_in[22];
  const float* ln2_b = (const float*)d_in[23];
  const float* fc_w  = (const float*)d_in[24];
  const float* fc_b  = (const float*)d_in[25];
  const float* pr_w  = (const float*)d_in[26];
  const float* pr_b  = (const float*)d_in[27];
  const float* lnf_w = (const float*)d_in[28];
  const float* lnf_b = (const float*)d_in[29];

  const size_t M1 = 1048576;
  float* ws     = (float*)d_ws;
  float* x      = ws;                    // [1024,1024] f32
  u16* qkvh  = (u16*)(x + M1);           // q,k: [32][512][64]; v: [32][64][512]
  u16* nbf   = qkvh + 3 * M1;            // [1024,1024] bf16
  u16* ybf   = nbf + M1;                 // [1024,1024] bf16
  u16* hmbf  = ybf + M1;                 // [1024,4096] bf16
  u16* xabf  = hmbf + 4 * M1;            // [1024,1024] bf16
  u16* wtebf = xabf + M1;                // [32000,1024] bf16
  u16* wT    = wtebf + (size_t)VV * CC;  // 16M bf16 per-layer transposed weights

  // per-layer wT offsets (elems) — squares are exactly z*M1 for z=0..7
  const size_t oQKV = 0, oWO = 3 * M1, oCQ = 4 * M1, oCKV = 5 * M1,
               oCWO = 7 * M1, oFC = 8 * M1, oPR = 12 * M1;

  embed_kernel<<<NTOK, 256, 0, stream>>>(idx, wte, wpe, x);
  convbf_kernel<<<(VV * CC / 4 + 255) / 256, 256, 0, stream>>>(wte, wtebf, VV * CC / 4);
  convbf_kernel<<<(NTOK * CC / 4 + 255) / 256, 256, 0, stream>>>(xa, xabf, NTOK * CC / 4);

  for (int l = 0; l < 6; ++l) {
    size_t wofs = (size_t)l * CC * CC;
    size_t bofs = (size_t)l * CC;
    size_t mofs = (size_t)l * CC * DFF_;

    // ---- weight prep: 3 launches (8 squares fused; fc; pr) ----
    wtrans8_kernel<<<dim3(32, 32, 8), 256, 0, stream>>>(
        sa_wq + wofs, sa_wk + wofs, sa_wv + wofs, sa_wo + wofs,
        ca_wq + wofs, ca_wk + wofs, ca_wv + wofs, ca_wo + wofs, wT);
    wtrans_kernel<<<dim3(128, 32), 256, 0, stream>>>(fc_w + mofs, wT + oFC, CC, DFF_);
    wtrans_kernel<<<dim3(32, 128), 256, 0, stream>>>(pr_w + mofs, wT + oPR, DFF_, CC);

    // ---- self attention ----
    ln_kernel<<<NTOK, 256, 0, stream>>>(x, ln1_w + bofs, ln1_b + bofs, nbf);
    gemm_bf16_kernel<4, 0><<<dim3(24, 8), 256, 0, stream>>>(
        nbf, wT + oQKV, sa_bq + bofs, sa_bk + bofs, sa_bv + bofs,
        (float*)qkvh, CC, 0, 0);
    attn_kernel<<<dim3(16, 32), 256, 0, stream>>>(qkvh, qkvh + M1, qkvh + 2 * M1, ybf);
    gemm_bf16_kernel<1, 0><<<dim3(8, 8), 256, 0, stream>>>(
        ybf, wT + oWO, sa_bo + bofs, nullptr, nullptr, x, CC, CC, 0);

    // ---- cross attention (ln_1 reused; causal mask kept, as in reference) ----
    ln_kernel<<<NTOK, 256, 0, stream>>>(x, ln1_w + bofs, ln1_b + bofs, nbf);
    gemm_bf16_kernel<4, 0><<<dim3(8, 8), 256, 0, stream>>>(
        nbf, wT + oCQ, ca_bq + bofs, nullptr, nullptr, (float*)qkvh, CC, 0, 0);
    gemm_bf16_kernel<4, 0><<<dim3(16, 8), 256, 0, stream>>>(
        xabf, wT + oCKV, nullptr, ca_bk + bofs, ca_bv + bofs,
        (float*)qkvh, CC, 0, 1);
    attn_kernel<<<dim3(16, 32), 256, 0, stream>>>(qkvh, qkvh + M1, qkvh + 2 * M1, ybf);
    gemm_bf16_kernel<1, 0><<<dim3(8, 8), 256, 0, stream>>>(
        ybf, wT + oCWO, ca_bo + bofs, nullptr, nullptr, x, CC, CC, 0);

    // ---- MLP ----
    ln_kernel<<<NTOK, 256, 0, stream>>>(x, ln2_w + bofs, ln2_b + bofs, nbf);
    gemm_bf16_kernel<2, 0><<<dim3(32, 8), 256, 0, stream>>>(
        nbf, wT + oFC, fc_b + (size_t)l * DFF_, nullptr, nullptr,
        (float*)hmbf, CC, DFF_, 0);
    gemm_bf16_kernel<1, 0><<<dim3(8, 8), 256, 0, stream>>>(
        hmbf, wT + oPR, pr_b + bofs, nullptr, nullptr, x, DFF_, CC, 0);
  }

  // ---- final LN + tied lm_head, bijective XCD-swizzled 1D grid ----
  ln_kernel<<<NTOK, 256, 0, stream>>>(x, lnf_w, lnf_b, nbf);
  gemm_bf16_kernel<0, 2><<<dim3(2000), 256, 0, stream>>>(
      nbf, wtebf, nullptr, nullptr, nullptr, (float*)d_out, CC, VV, 0);
}

// Round 8
// 1667.627 us; speedup vs baseline: 4.6467x; 1.3603x over previous
//
#include <hip/hip_runtime.h>
#include <math.h>

#define CC   1024
#define HH   16
#define DH   64
#define TT   512
#define NTOK 1024     // B*T
#define DFF_ 4096
#define VV   32000
#define QKSCALE 0.125f   // 1/sqrt(64)

typedef unsigned short u16;
typedef __attribute__((ext_vector_type(8))) short short8;
typedef __attribute__((ext_vector_type(4))) float f32x4;

__device__ __forceinline__ u16 f2bf(float f) {   // RNE fp32->bf16
  union { float f; unsigned u; } v; v.f = f;
  unsigned r = v.u + 0x7FFFu + ((v.u >> 16) & 1u);
  return (u16)(r >> 16);
}
__device__ __forceinline__ float gelu_f(float h) {
  return 0.5f * h * (1.0f + tanhf(0.7978845608028654f * (h + 0.044715f * h * h * h)));
}

// async global->LDS, 16B per lane; dest = wave-uniform base + lane*16
#define GLD16(gp, lp) __builtin_amdgcn_global_load_lds( \
    (const __attribute__((address_space(1))) void*)(gp), \
    (__attribute__((address_space(3))) void*)(lp), 16, 0, 0)

#define MFMA(a, b, c) __builtin_amdgcn_mfma_f32_16x16x32_bf16(a, b, c, 0, 0, 0)

// ---------------- embedding ----------------------------------------------
__global__ __launch_bounds__(256) void embed_kernel(
    const int* __restrict__ idx, const float* __restrict__ wte,
    const float* __restrict__ wpe, float* __restrict__ x) {
  int row = blockIdx.x;
  int t = row & (TT - 1);
  int id = idx[row];
  const float4* a = (const float4*)(wte + (size_t)id * CC);
  const float4* p = (const float4*)(wpe + (size_t)t * CC);
  float4* o = (float4*)(x + (size_t)row * CC);
  int c = threadIdx.x;
  float4 va = a[c], vp = p[c];
  float4 ov;
  ov.x = va.x + vp.x; ov.y = va.y + vp.y; ov.z = va.z + vp.z; ov.w = va.w + vp.w;
  o[c] = ov;
}

// ---------------- layernorm (fp32 in -> bf16 out) ------------------------
__global__ __launch_bounds__(256) void ln_kernel(
    const float* __restrict__ x, const float* __restrict__ w,
    const float* __restrict__ b, u16* __restrict__ out) {
  int row = blockIdx.x, tid = threadIdx.x;
  float4 v = ((const float4*)(x + (size_t)row * CC))[tid];
  float s  = v.x + v.y + v.z + v.w;
  float sq = fmaf(v.x, v.x, fmaf(v.y, v.y, fmaf(v.z, v.z, v.w * v.w)));
  for (int o = 32; o > 0; o >>= 1) { s += __shfl_down(s, o); sq += __shfl_down(sq, o); }
  __shared__ float rs[4], rq[4];
  int wid = tid >> 6, lane = tid & 63;
  if (lane == 0) { rs[wid] = s; rq[wid] = sq; }
  __syncthreads();
  s  = rs[0] + rs[1] + rs[2] + rs[3];
  sq = rq[0] + rq[1] + rq[2] + rq[3];
  float mean = s * (1.0f / CC);
  float var  = sq * (1.0f / CC) - mean * mean;
  float rstd = 1.0f / sqrtf(var + 1e-5f);
  float4 wv = ((const float4*)w)[tid];
  float4 bv = ((const float4*)b)[tid];
  ushort4 o;
  o.x = f2bf((v.x - mean) * rstd * wv.x + bv.x);
  o.y = f2bf((v.y - mean) * rstd * wv.y + bv.y);
  o.z = f2bf((v.z - mean) * rstd * wv.z + bv.z);
  o.w = f2bf((v.w - mean) * rstd * wv.w + bv.w);
  ((ushort4*)(out + (size_t)row * CC))[tid] = o;
}

// ---------------- per-layer fused weight prep: 16x 1024^2 transposes -----
// z 0-7: square weights  (src stride 1024 -> dst wT+z*M1, stride 1024)
// z 8-11: fc col-slices  (src fc+s*1024, stride 4096 -> dst oFC+s*M1, stride 1024)
// z 12-15: pr row-slices (src pr+s*M1, stride 1024 -> dst oPR+s*1024, stride 4096)
__global__ __launch_bounds__(256) void wtrans16_kernel(
    const float* __restrict__ w0, const float* __restrict__ w1,
    const float* __restrict__ w2, const float* __restrict__ w3,
    const float* __restrict__ w4, const float* __restrict__ w5,
    const float* __restrict__ w6, const float* __restrict__ w7,
    const float* __restrict__ fc, const float* __restrict__ pr,
    u16* __restrict__ wt) {
  const size_t M1 = 1048576;
  int z = blockIdx.z;
  const float* src;
  size_t doff;
  int sstr, dstr;
  if (z < 8) {
    src = z == 0 ? w0 : z == 1 ? w1 : z == 2 ? w2 : z == 3 ? w3
        : z == 4 ? w4 : z == 5 ? w5 : z == 6 ? w6 : w7;
    sstr = 1024; doff = (size_t)z * M1; dstr = 1024;
  } else if (z < 12) {
    int s = z - 8;
    src = fc + (size_t)s * 1024; sstr = 4096;
    doff = 8 * M1 + (size_t)s * M1; dstr = 1024;
  } else {
    int s = z - 12;
    src = pr + (size_t)s * M1; sstr = 1024;
    doff = 12 * M1 + (size_t)s * 1024; dstr = 4096;
  }
  __shared__ float t[32][33];
  int bx = blockIdx.x * 32, by = blockIdx.y * 32;
  int c = threadIdx.x & 31, r = threadIdx.x >> 5;
#pragma unroll
  for (int i = 0; i < 4; ++i)
    t[r + i * 8][c] = src[(size_t)(by + r + i * 8) * sstr + bx + c];
  __syncthreads();
#pragma unroll
  for (int i = 0; i < 4; ++i)
    wt[doff + (size_t)(bx + r + i * 8) * dstr + by + c] = f2bf(t[c][r + i * 8]);
}

// ---------------- elementwise f32 -> bf16 --------------------------------
__global__ __launch_bounds__(256) void convbf_kernel(
    const float* __restrict__ in, u16* __restrict__ out, int n4) {
  int i = blockIdx.x * 256 + threadIdx.x;
  if (i < n4) {
    float4 v = ((const float4*)in)[i];
    ushort4 o; o.x = f2bf(v.x); o.y = f2bf(v.y); o.z = f2bf(v.z); o.w = f2bf(v.w);
    ((ushort4*)out)[i] = o;
  }
}

// ---------------- bf16 MFMA GEMM, BK=64, XOR-swizzled LDS ----------------
// C[M,N](ldc) = epi(A[M,K] @ B^T + bias);  A[M,K], B[N,K] bf16 row-major.
// Tile BM x BN, 4 waves of (BM/2)x(BN/2).
// EPI: 0=store f32(+bias), 1=f32 +=(+bias) residual, 2=bf16 gelu(+bias),
//      4=bf16 per-head scatter (bias/bias2/bias3 per 1024-col chunk)
// MODE: 0 = normal grid; 2 = lm_head 1D grid, bijective XCD swizzle
template <int EPI, int MODE, int BM, int BN>
__global__ __launch_bounds__(256) void gemm_bf16_kernel(
    const u16* __restrict__ A, const u16* __restrict__ B,
    const float* __restrict__ bias, const float* __restrict__ bias2,
    const float* __restrict__ bias3, float* __restrict__ Cm,
    int K, int ldc, int whichbase) {
  constexpr int WM = BM / 2, WN = BN / 2, MF = WM / 16, NF = WN / 16;
  constexpr int PA = BM / 32, PB = BN / 32;
  __shared__ u16 As[BM * 64];
  __shared__ u16 Bs[BN * 64];
  int tid = threadIdx.x;
  int lane = tid & 63, wave = tid >> 6;
  int wr = wave >> 1, wc = wave & 1;
  int row0, col0;
  if (MODE == 2) {
    int id = blockIdx.x;                 // 0..1999
    int wg = (id & 7) * 250 + (id >> 3); // bijective: each XCD -> 250 wgs
    row0 = (wg & 7) * BM;
    col0 = (wg >> 3) * BN;
  } else {
    row0 = blockIdx.y * BM;
    col0 = blockIdx.x * BN;
  }
  f32x4 acc[MF][NF];
#pragma unroll
  for (int m = 0; m < MF; ++m)
#pragma unroll
    for (int n = 0; n < NF; ++n) acc[m][n] = (f32x4){0.f, 0.f, 0.f, 0.f};

  int srow = tid >> 3;                       // staging row within 32-row pass
  int sblk = (tid & 7) ^ ((tid >> 3) & 7);   // pre-swizzled source 16B-blk
  const u16* Ab = A + (size_t)row0 * K;
  const u16* Bb = B + (size_t)col0 * K;
  int arow = wr * WM + (lane & 15);
  int brow = wc * WN + (lane & 15);
  int g8 = lane >> 4;

  for (int k0 = 0; k0 < K; k0 += 64) {
#pragma unroll
    for (int p = 0; p < PA; ++p)
      GLD16(Ab + (size_t)(p * 32 + srow) * K + k0 + sblk * 8,
            &As[p * 2048 + wave * 512]);
#pragma unroll
    for (int p = 0; p < PB; ++p)
      GLD16(Bb + (size_t)(p * 32 + srow) * K + k0 + sblk * 8,
            &Bs[p * 2048 + wave * 512]);
    __syncthreads();
#pragma unroll
    for (int ks = 0; ks < 2; ++ks) {
      short8 af[MF], bg[NF];
#pragma unroll
      for (int m = 0; m < MF; ++m) {
        int row = arow + m * 16;
        af[m] = *(const short8*)&As[row * 64 + (((ks * 4 + g8) ^ (row & 7)) << 3)];
      }
#pragma unroll
      for (int n = 0; n < NF; ++n) {
        int row = brow + n * 16;
        bg[n] = *(const short8*)&Bs[row * 64 + (((ks * 4 + g8) ^ (row & 7)) << 3)];
      }
#pragma unroll
      for (int m = 0; m < MF; ++m)
#pragma unroll
        for (int n = 0; n < NF; ++n)
          acc[m][n] = MFMA(af[m], bg[n], acc[m][n]);
    }
    __syncthreads();
  }

  int r0 = row0 + wr * WM + g8 * 4;
  int c0 = col0 + wc * WN + (lane & 15);

  if (EPI == 4) {
    // scatter to per-head layouts: q/k [bh][t][d], v [bh][d][t]
    u16* qb = (u16*)Cm;
#pragma unroll
    for (int m = 0; m < MF; ++m)
#pragma unroll
      for (int n = 0; n < NF; ++n) {
        int j = c0 + n * 16;
        int which = whichbase + (j >> 10);
        const float* bp = (j >> 10) == 0 ? bias : ((j >> 10) == 1 ? bias2 : bias3);
        float bj = bp ? bp[j & 1023] : 0.0f;
        int h = (j & 1023) >> 6, d = j & 63;
        int trow0 = r0 + m * 16;
        int b = trow0 >> 9, t0 = trow0 & 511;
        int bh = b * 16 + h;
        u16 vals[4];
#pragma unroll
        for (int r = 0; r < 4; ++r) vals[r] = f2bf(acc[m][n][r] + bj);
        if (which < 2) {
          u16* dst = qb + (size_t)which * 1048576 + (size_t)bh * 32768 + (size_t)t0 * 64 + d;
#pragma unroll
          for (int r = 0; r < 4; ++r) dst[(size_t)r * 64] = vals[r];
        } else {
          u16* dst = qb + 2 * 1048576 + (size_t)bh * 32768 + (size_t)d * 512 + t0;
          *(ushort4*)dst = *(ushort4*)vals;
        }
      }
    return;
  }

  float bj[NF];
#pragma unroll
  for (int n = 0; n < NF; ++n)
    bj[n] = bias ? bias[c0 + n * 16] : 0.0f;
  u16* Cb = (u16*)Cm;
#pragma unroll
  for (int m = 0; m < MF; ++m)
#pragma unroll
    for (int n = 0; n < NF; ++n)
#pragma unroll
      for (int r = 0; r < 4; ++r) {
        size_t off = (size_t)(r0 + m * 16 + r) * ldc + c0 + n * 16;
        float v = acc[m][n][r] + bj[n];
        if (EPI == 0) Cm[off] = v;
        else if (EPI == 1) Cm[off] += v;
        else if (EPI == 2) Cb[off] = f2bf(gelu_f(v));
      }
}

// ---------------- fused flash attention (causal, incl. cross per ref) ----
// q,k: [32 bh][512 t][64 d] bf16;  v: [32 bh][64 d][512 t] bf16
// y: [1024 tok][1024 C] bf16.  Grid (16 q-tiles, 32 bh), 256 threads.
__global__ __launch_bounds__(256) void attn_kernel(
    const u16* __restrict__ qh, const u16* __restrict__ kh,
    const u16* __restrict__ vt, u16* __restrict__ y) {
  __shared__ u16 P[32 * 512];             // swizzled probs
  __shared__ float smax[4][32], ssum[4][32];
  int tid = threadIdx.x, lane = tid & 63, w = tid >> 6;
  int bx = blockIdx.x, bh = blockIdx.y;
  int q0 = bx * 32;
  int b = bh >> 4, h = bh & 15;
  const u16* qb = qh + (size_t)bh * 32768;
  const u16* kb = kh + (size_t)bh * 32768;
  const u16* vb = vt + (size_t)bh * 32768;
  int g = lane >> 4, c = lane & 15;

  short8 a[2][2];
#pragma unroll
  for (int rt = 0; rt < 2; ++rt)
#pragma unroll
    for (int ks = 0; ks < 2; ++ks)
      a[rt][ks] = *(const short8*)(qb + (size_t)(q0 + rt * 16 + c) * 64 + ks * 32 + g * 8);

  int lim = q0 + 31;
  int nct = (lim - w * 128) / 16 + 1;
  if (nct > 8) nct = 8;
  if (nct < 0) nct = 0;
  f32x4 s[2][8];
#pragma unroll
  for (int rt = 0; rt < 2; ++rt)
#pragma unroll
    for (int ct = 0; ct < 8; ++ct) s[rt][ct] = (f32x4){0.f, 0.f, 0.f, 0.f};
  for (int ct = 0; ct < nct; ++ct) {
    int n0 = w * 128 + ct * 16;
#pragma unroll
    for (int ks = 0; ks < 2; ++ks) {
      short8 bf = *(const short8*)(kb + (size_t)(n0 + c) * 64 + ks * 32 + g * 8);
      s[0][ct] = MFMA(a[0][ks], bf, s[0][ct]);
      s[1][ct] = MFMA(a[1][ks], bf, s[1][ct]);
    }
  }

  float mx[2][4];
#pragma unroll
  for (int rt = 0; rt < 2; ++rt)
#pragma unroll
    for (int r = 0; r < 4; ++r) mx[rt][r] = -1e30f;
  for (int ct = 0; ct < nct; ++ct) {
    int col = w * 128 + ct * 16 + c;
#pragma unroll
    for (int rt = 0; rt < 2; ++rt)
#pragma unroll
      for (int r = 0; r < 4; ++r) {
        int trow = q0 + rt * 16 + g * 4 + r;
        float v = s[rt][ct][r] * QKSCALE;
        if (col > trow) v = -1e30f;
        s[rt][ct][r] = v;
        mx[rt][r] = fmaxf(mx[rt][r], v);
      }
  }
#pragma unroll
  for (int off = 1; off < 16; off <<= 1)
#pragma unroll
    for (int rt = 0; rt < 2; ++rt)
#pragma unroll
      for (int r = 0; r < 4; ++r) mx[rt][r] = fmaxf(mx[rt][r], __shfl_xor(mx[rt][r], off));
  if (c == 0)
#pragma unroll
    for (int rt = 0; rt < 2; ++rt)
#pragma unroll
      for (int r = 0; r < 4; ++r) smax[w][rt * 16 + g * 4 + r] = mx[rt][r];
  __syncthreads();

  float m_[2][4], sum[2][4];
#pragma unroll
  for (int rt = 0; rt < 2; ++rt)
#pragma unroll
    for (int r = 0; r < 4; ++r) {
      int row = rt * 16 + g * 4 + r;
      m_[rt][r] = fmaxf(fmaxf(smax[0][row], smax[1][row]), fmaxf(smax[2][row], smax[3][row]));
      sum[rt][r] = 0.f;
    }
  for (int ct = 0; ct < nct; ++ct) {
    int col = w * 128 + ct * 16 + c;
    int blk = col >> 3, cl = col & 7;
#pragma unroll
    for (int rt = 0; rt < 2; ++rt)
#pragma unroll
      for (int r = 0; r < 4; ++r) {
        float p = __expf(s[rt][ct][r] - m_[rt][r]);
        sum[rt][r] += p;
        int row = rt * 16 + g * 4 + r;
        int hsh = (row ^ (row >> 2)) & 7;
        P[row * 512 + ((blk ^ hsh) << 3) + cl] = f2bf(p);
      }
  }
#pragma unroll
  for (int off = 1; off < 16; off <<= 1)
#pragma unroll
    for (int rt = 0; rt < 2; ++rt)
#pragma unroll
      for (int r = 0; r < 4; ++r) sum[rt][r] += __shfl_xor(sum[rt][r], off);
  if (c == 0)
#pragma unroll
    for (int rt = 0; rt < 2; ++rt)
#pragma unroll
      for (int r = 0; r < 4; ++r) ssum[w][rt * 16 + g * 4 + r] = sum[rt][r];
  __syncthreads();

  float li[2][4];
#pragma unroll
  for (int rt = 0; rt < 2; ++rt)
#pragma unroll
    for (int r = 0; r < 4; ++r) {
      int row = rt * 16 + g * 4 + r;
      li[rt][r] = 1.0f / (ssum[0][row] + ssum[1][row] + ssum[2][row] + ssum[3][row]);
    }

  int rt2 = w >> 1, nh = w & 1;
  f32x4 o[2];
  o[0] = (f32x4){0.f, 0.f, 0.f, 0.f};
  o[1] = (f32x4){0.f, 0.f, 0.f, 0.f};
  int nks = bx + 1;
  int prow = rt2 * 16 + c;
  int phsh = (prow ^ (prow >> 2)) & 7;
  for (int ks = 0; ks < nks; ++ks) {
    short8 pa = *(const short8*)&P[prow * 512 + (((ks * 4 + g) ^ phsh) << 3)];
#pragma unroll
    for (int nt = 0; nt < 2; ++nt) {
      int d = nh * 32 + nt * 16 + c;
      short8 vf = *(const short8*)(vb + (size_t)d * 512 + ks * 32 + g * 8);
      o[nt] = MFMA(pa, vf, o[nt]);
    }
  }
#pragma unroll
  for (int nt = 0; nt < 2; ++nt)
#pragma unroll
    for (int r = 0; r < 4; ++r) {
      int trow = q0 + rt2 * 16 + g * 4 + r;
      float val = o[nt][r] * li[rt2][r];
      y[(size_t)(b * 512 + trow) * 1024 + h * 64 + nh * 32 + nt * 16 + c] = f2bf(val);
    }
}

// ---------------- launch ---------------------------------------------------
extern "C" void kernel_launch(void* const* d_in, const int* in_sizes, int n_in,
                              void* d_out, int out_size, void* d_ws, size_t ws_size,
                              hipStream_t stream) {
  const int*   idx   = (const int*)d_in[0];
  const float* xa    = (const float*)d_in[1];
  const float* wte   = (const float*)d_in[2];
  const float* wpe   = (const float*)d_in[3];
  const float* ln1_w = (const float*)d_in[4];
  const float* ln1_b = (const float*)d_in[5];
  const float* sa_wq = (const float*)d_in[6];
  const float* sa_bq = (const float*)d_in[7];
  const float* sa_wk = (const float*)d_in[8];
  const float* sa_bk = (const float*)d_in[9];
  const float* sa_wv = (const float*)d_in[10];
  const float* sa_bv = (const float*)d_in[11];
  const float* sa_wo = (const float*)d_in[12];
  const float* sa_bo = (const float*)d_in[13];
  const float* ca_wq = (const float*)d_in[14];
  const float* ca_bq = (const float*)d_in[15];
  const float* ca_wk = (const float*)d_in[16];
  const float* ca_bk = (const float*)d_in[17];
  const float* ca_wv = (const float*)d_in[18];
  const float* ca_bv = (const float*)d_in[19];
  const float* ca_wo = (const float*)d_in[20];
  const float* ca_bo = (const float*)d_in[21];
  const float* ln2_w = (const float*)d_in[22];
  const float* ln2_b = (const float*)d_in[23];
  const float* fc_w  = (const float*)d_in[24];
  const float* fc_b  = (const float*)d_in[25];
  const float* pr_w  = (const float*)d_in[26];
  const float* pr_b  = (const float*)d_in[27];
  const float* lnf_w = (const float*)d_in[28];
  const float* lnf_b = (const float*)d_in[29];

  const size_t M1 = 1048576;
  float* ws     = (float*)d_ws;
  float* x      = ws;                    // [1024,1024] f32
  u16* qkvh  = (u16*)(x + M1);           // q,k: [32][512][64]; v: [32][64][512]
  u16* nbf   = qkvh + 3 * M1;            // [1024,1024] bf16
  u16* ybf   = nbf + M1;                 // [1024,1024] bf16
  u16* hmbf  = ybf + M1;                 // [1024,4096] bf16
  u16* xabf  = hmbf + 4 * M1;            // [1024,1024] bf16
  u16* wtebf = xabf + M1;                // [32000,1024] bf16
  u16* wT    = wtebf + (size_t)VV * CC;  // 16M bf16 per-layer transposed weights

  const size_t oQKV = 0, oWO = 3 * M1, oCQ = 4 * M1, oCKV = 5 * M1,
               oCWO = 7 * M1, oFC = 8 * M1, oPR = 12 * M1;

  embed_kernel<<<NTOK, 256, 0, stream>>>(idx, wte, wpe, x);
  convbf_kernel<<<(VV * CC / 4 + 255) / 256, 256, 0, stream>>>(wte, wtebf, VV * CC / 4);
  convbf_kernel<<<(NTOK * CC / 4 + 255) / 256, 256, 0, stream>>>(xa, xabf, NTOK * CC / 4);

  for (int l = 0; l < 6; ++l) {
    size_t wofs = (size_t)l * CC * CC;
    size_t bofs = (size_t)l * CC;
    size_t mofs = (size_t)l * CC * DFF_;

    // ---- weight prep: ONE launch (8 squares + 4 fc slices + 4 pr slices)
    wtrans16_kernel<<<dim3(32, 32, 16), 256, 0, stream>>>(
        sa_wq + wofs, sa_wk + wofs, sa_wv + wofs, sa_wo + wofs,
        ca_wq + wofs, ca_wk + wofs, ca_wv + wofs, ca_wo + wofs,
        fc_w + mofs, pr_w + mofs, wT);

    // ---- self attention ----
    ln_kernel<<<NTOK, 256, 0, stream>>>(x, ln1_w + bofs, ln1_b + bofs, nbf);
    gemm_bf16_kernel<4, 0, 64, 128><<<dim3(24, 16), 256, 0, stream>>>(
        nbf, wT + oQKV, sa_bq + bofs, sa_bk + bofs, sa_bv + bofs,
        (float*)qkvh, CC, 0, 0);
    attn_kernel<<<dim3(16, 32), 256, 0, stream>>>(qkvh, qkvh + M1, qkvh + 2 * M1, ybf);
    gemm_bf16_kernel<1, 0, 64, 64><<<dim3(16, 16), 256, 0, stream>>>(
        ybf, wT + oWO, sa_bo + bofs, nullptr, nullptr, x, CC, CC, 0);

    // ---- cross attention (ln_1 reused; causal mask kept, as in reference) ----
    ln_kernel<<<NTOK, 256, 0, stream>>>(x, ln1_w + bofs, ln1_b + bofs, nbf);
    gemm_bf16_kernel<4, 0, 64, 64><<<dim3(16, 16), 256, 0, stream>>>(
        nbf, wT + oCQ, ca_bq + bofs, nullptr, nullptr, (float*)qkvh, CC, 0, 0);
    gemm_bf16_kernel<4, 0, 64, 128><<<dim3(16, 16), 256, 0, stream>>>(
        xabf, wT + oCKV, ca_bk + bofs, ca_bv + bofs, nullptr,
        (float*)qkvh, CC, 0, 1);
    attn_kernel<<<dim3(16, 32), 256, 0, stream>>>(qkvh, qkvh + M1, qkvh + 2 * M1, ybf);
    gemm_bf16_kernel<1, 0, 64, 64><<<dim3(16, 16), 256, 0, stream>>>(
        ybf, wT + oCWO, ca_bo + bofs, nullptr, nullptr, x, CC, CC, 0);

    // ---- MLP ----
    ln_kernel<<<NTOK, 256, 0, stream>>>(x, ln2_w + bofs, ln2_b + bofs, nbf);
    gemm_bf16_kernel<2, 0, 128, 128><<<dim3(32, 8), 256, 0, stream>>>(
        nbf, wT + oFC, fc_b + (size_t)l * DFF_, nullptr, nullptr,
        (float*)hmbf, CC, DFF_, 0);
    gemm_bf16_kernel<1, 0, 64, 64><<<dim3(16, 16), 256, 0, stream>>>(
        hmbf, wT + oPR, pr_b + bofs, nullptr, nullptr, x, DFF_, CC, 0);
  }

  // ---- final LN + tied lm_head, bijective XCD-swizzled 1D grid ----
  ln_kernel<<<NTOK, 256, 0, stream>>>(x, lnf_w, lnf_b, nbf);
  gemm_bf16_kernel<0, 2, 128, 128><<<dim3(2000), 256, 0, stream>>>(
      nbf, wtebf, nullptr, nullptr, nullptr, (float*)d_out, CC, VV, 0);
}